// Round 1
// baseline (2999.584 us; speedup 1.0000x reference)
//
#include <hip/hip_runtime.h>
#include <math.h>

#define DD   46
#define LL0  4000
#define LL1  600
#define CATV 250
#define NC   50
#define NJ   100
#define HC   256
#define H2C  128
#define NPOS (LL0*NJ)
#define EPSV 1e-5f

// ---- workspace float offsets ----
#define W_MEAN0   0
#define W_MEANH   64
#define W_MEANL   128
#define W_RM4     192
#define W_RM5     256
#define W_S1      320
#define W_HBAR    384
#define W_RAWMH   448
#define W_RAWML   (W_RAWMH+2304)
#define W_H       (W_RAWML+2304)
#define W_L       (W_H+2304)
#define W_BN1S    (W_L+2304)          // 256 sum, then 256 sumsq
#define W_SC1     (W_BN1S+512)        // 256 scale, then 256 shift
#define W_BN2S    (W_SC1+512)         // 128 sum, 128 sumsq
#define W_SC2     (W_BN2S+256)        // 128 scale, 128 shift
#define W_A0      11264
#define W_LDIF    (W_A0+DD*LL0)
#define W_LMUL    (W_LDIF+DD*LL0)
#define W_TOTAL   (W_LMUL+DD*LL0)

__device__ __forceinline__ float sigf(float x){ return 1.0f/(1.0f+__expf(-x)); }

__device__ float blockReduceSum(float v, float* sm){
  int tid=threadIdx.x;
  sm[tid]=v; __syncthreads();
  for(int s=128;s>0;s>>=1){ if(tid<s) sm[tid]+=sm[tid+s]; __syncthreads(); }
  float r=sm[0]; __syncthreads();
  return r;
}

// zero BN stat + param region
__global__ void k_zero(float* ws){
  for(int e=threadIdx.x;e<1536;e+=256) ws[W_BN1S+e]=0.f;
}

// per-channel means of z0, z1H, z1L (pre-ECA inputs)
__global__ void k_colmeans(const float* z0, const float* z1, float* ws){
  __shared__ float sm[256];
  int d=blockIdx.x, tid=threadIdx.x;
  float s0=0.f; for(int i=tid;i<LL0;i+=256) s0+=z0[i*DD+d];
  float sH=0.f; for(int k=tid;k<CATV;k+=256) sH+=z1[k*DD+d];
  float sL=0.f; for(int k=CATV+tid;k<LL1;k+=256) sL+=z1[k*DD+d];
  float r0=blockReduceSum(s0,sm);
  float rH=blockReduceSum(sH,sm);
  float rL=blockReduceSum(sL,sm);
  if(tid==0){
    ws[W_MEAN0+d]=r0/(float)LL0;
    ws[W_MEANH+d]=rH/(float)CATV;
    ws[W_MEANL+d]=rL/(float)(LL1-CATV);
  }
}

// raw pair-difference means (pre-scale): rawmH[d][i] = mean_j |v[cdr_i]-v[not_j]|
__global__ void k_pairmeans(const float* z1, const int* cdrH, const int* notH,
                            const int* cdrL, const int* notL,
                            int nCdrH,int nNotH,int nCdrL,int nNotL, float* ws){
  __shared__ float v[LL1];
  __shared__ float sm[256];
  int d=blockIdx.x, tid=threadIdx.x;
  for(int k=tid;k<LL1;k+=256) v[k]=z1[k*DD+d];
  __syncthreads();
  float partH=0.f, partL=0.f;
  for(int i=tid;i<nCdrH;i+=256){
    float c=v[cdrH[i]]; float s=0.f;
    for(int j=0;j<nNotH;j++) s+=fabsf(c-v[notH[j]]);
    s/= (float)nNotH;
    ws[W_RAWMH+d*NC+i]=s; partH+=s;
  }
  for(int i=tid;i<nCdrL;i+=256){
    float c=v[CATV+cdrL[i]]; float s=0.f;
    for(int j=0;j<nNotL;j++) s+=fabsf(c-v[CATV+notL[j]]);
    s/= (float)nNotL;
    ws[W_RAWML+d*NC+i]=s; partL+=s;
  }
  float rH=blockReduceSum(partH,sm);
  float rL=blockReduceSum(partL,sm);
  if(tid==0){ ws[W_RM4+d]=rH/(float)nCdrH; ws[W_RM5+d]=rL/(float)nCdrL; }
}

__device__ __forceinline__ float conv3(const float* a, int d, const float* w){
  float acc = w[1]*a[d];
  if(d>0)    acc += w[0]*a[d-1];
  if(d<DD-1) acc += w[2]*a[d+1];
  return acc;
}

// all sigmoid scales + final h, l, hbar
__global__ void k_scales(const float* w1,const float* w2,const float* w3,
                         const float* w4,const float* w5, float* ws){
  __shared__ float m0[DD], mH[DD], mL[DD];
  __shared__ float s1s[DD],s2s[DD],s3s[DD],s4s[DD],s5s[DD],y4[DD],y5[DD];
  int tid=threadIdx.x;
  if(tid<DD){ m0[tid]=ws[W_MEAN0+tid]; mH[tid]=ws[W_MEANH+tid]; mL[tid]=ws[W_MEANL+tid]; }
  __syncthreads();
  if(tid<DD){
    s1s[tid]=sigf(conv3(m0,tid,w1));
    s2s[tid]=sigf(conv3(mH,tid,w2));
    s3s[tid]=sigf(conv3(mL,tid,w3));
  }
  __syncthreads();
  if(tid<DD){ y4[tid]=s2s[tid]*ws[W_RM4+tid]; y5[tid]=s3s[tid]*ws[W_RM5+tid]; }
  __syncthreads();
  if(tid<DD){
    s4s[tid]=sigf(conv3(y4,tid,w4));
    s5s[tid]=sigf(conv3(y5,tid,w5));
    ws[W_S1+tid]=s1s[tid];
  }
  __syncthreads();
  for(int e=tid;e<DD*NC;e+=256){
    int d=e/NC;
    ws[W_H+e]=s4s[d]*s2s[d]*ws[W_RAWMH+e];
    ws[W_L+e]=s5s[d]*s3s[d]*ws[W_RAWML+e];
  }
  __syncthreads();
  if(tid<DD){
    float s=0.f;
    for(int j=0;j<NC;j++) s+=ws[W_H+tid*NC+j];
    ws[W_HBAR+tid]=s/(float)NC;
  }
}

// a0 = s1*z0 ; Ldif = mean_j |a0-h_j| ; Lmul = a0*hbar
__global__ void k_a0(const float* z0, float* ws){
  __shared__ float hs[NC];
  int b=blockIdx.x; int d=b>>4; int i=((b&15)<<8)+threadIdx.x;
  if(threadIdx.x<NC) hs[threadIdx.x]=ws[W_H+d*NC+threadIdx.x];
  __syncthreads();
  if(i<LL0){
    float a=ws[W_S1+d]*z0[i*DD+d];
    float s=0.f;
    #pragma unroll
    for(int j=0;j<NC;j++) s+=fabsf(a-hs[j]);
    ws[W_A0 +d*LL0+i]=a;
    ws[W_LDIF+d*LL0+i]=s*(1.0f/(float)NC);
    ws[W_LMUL+d*LL0+i]=a*ws[W_HBAR+d];
  }
}

// build the 92x100 feature tile for position i into LDS
__device__ __forceinline__ void build_xc(float (*xc)[92], float* av, float* dv, float* mv,
                                         const float* ws, int i){
  int tid=threadIdx.x;
  if(tid<DD){
    av[tid]=ws[W_A0 +tid*LL0+i];
    dv[tid]=ws[W_LDIF+tid*LL0+i];
    mv[tid]=ws[W_LMUL+tid*LL0+i];
  }
  __syncthreads();
  for(int e=tid;e<NJ*92;e+=256){
    int j=e/92, c=e-j*92;
    int d=(c<DD)?c:c-DD;
    float x;
    if(j<NC){
      float hv=ws[W_H+d*NC+j];
      x=(c<DD)?fabsf(av[d]-hv):av[d]*hv;
    }else{
      float lv=ws[W_L+d*NC+(j-NC)];
      x=(c<DD)?fabsf(dv[d]-lv):fabsf(mv[d]-lv);
    }
    xc[j][c]=x;
  }
  __syncthreads();
}

// pass A: conv1 + relu, accumulate BN1 sum/sumsq (no store)
__global__ __launch_bounds__(256) void k_passA(const float* ws, const float* conv_w,
                                               const float* conv_b, float* bnsum){
  __shared__ float xc[NJ][92];
  __shared__ float av[DD],dv[DD],mv[DD];
  int i=blockIdx.x, tid=threadIdx.x;
  build_xc(xc,av,dv,mv,ws,i);
  int o=tid;
  float w[92];
  #pragma unroll
  for(int c=0;c<92;c++) w[c]=conv_w[o*92+c];
  float bias=conv_b[o];
  float s=0.f,ss=0.f;
  for(int j=0;j<NJ;j++){
    float acc=bias;
    #pragma unroll
    for(int c=0;c<92;c++) acc+=w[c]*xc[j][c];
    float r=fmaxf(acc,0.f);
    s+=r; ss+=r*r;
  }
  atomicAdd(&bnsum[o],s); atomicAdd(&bnsum[HC+o],ss);
}

// BN params: scale = g*rsqrt(var+eps), shift = b - mu*scale
__global__ void k_bnparams(float* ws, const float* g, const float* b,
                           int nch, int sumoff, int scoff){
  int o=threadIdx.x;
  if(o<nch){
    float mu =ws[sumoff+o]    *(1.0f/(float)NPOS);
    float ex2=ws[sumoff+nch+o]*(1.0f/(float)NPOS);
    float var=ex2-mu*mu; if(var<0.f) var=0.f;
    float sc=g[o]*rsqrtf(var+EPSV);
    ws[scoff+o]=sc;
    ws[scoff+nch+o]=b[o]-mu*sc;
  }
}

// pass B: conv1 recompute + BN1 + conv2 + relu; BN2 stats; write pre-BN2 to out
__global__ __launch_bounds__(256) void k_passB(const float* ws, const float* conv_w,
      const float* conv_b, const float* conv2_w, const float* conv2_b,
      float* out, float* bn2sum){
  __shared__ float xc[NJ][92];
  __shared__ float c1s[NJ][HC];
  __shared__ float av[DD],dv[DD],mv[DD];
  int i=blockIdx.x, tid=threadIdx.x;
  build_xc(xc,av,dv,mv,ws,i);
  {
    int o=tid;
    float w[92];
    #pragma unroll
    for(int c=0;c<92;c++) w[c]=conv_w[o*92+c];
    float bias=conv_b[o];
    float sc=ws[W_SC1+o], sh=ws[W_SC1+HC+o];
    for(int j=0;j<NJ;j++){
      float acc=bias;
      #pragma unroll
      for(int c=0;c<92;c++) acc+=w[c]*xc[j][c];
      float r=fmaxf(acc,0.f);
      c1s[j][o]=r*sc+sh;
    }
  }
  __syncthreads();
  int o2=tid&127, g=tid>>7;
  float acc2[NC];
  {
    float bias2=conv2_b[o2];
    #pragma unroll
    for(int jj=0;jj<NC;jj++) acc2[jj]=bias2;
    const float4* w2r=(const float4*)(conv2_w+o2*HC);
    for(int k4=0;k4<HC/4;k4++){
      float4 wv=w2r[k4];
      const float* base=&c1s[g*NC][0]+k4*4;
      #pragma unroll
      for(int jj=0;jj<NC;jj++){
        float4 cv=*(const float4*)(base+jj*HC);
        acc2[jj]+=wv.x*cv.x+wv.y*cv.y+wv.z*cv.z+wv.w*cv.w;
      }
    }
  }
  float s=0.f,ss=0.f;
  #pragma unroll
  for(int jj=0;jj<NC;jj++){
    float r=fmaxf(acc2[jj],0.f); acc2[jj]=r;
    s+=r; ss+=r*r;
  }
  atomicAdd(&bn2sum[o2],s); atomicAdd(&bn2sum[H2C+o2],ss);
  __syncthreads();                   // all c1s reads done
  float* res=&c1s[0][0];             // reuse as res[128][101]
  #pragma unroll
  for(int jj=0;jj<NC;jj++) res[o2*101+g*NC+jj]=acc2[jj];
  __syncthreads();
  for(int e=tid;e<H2C*NJ;e+=256){
    int oo=e/NJ, j=e-oo*NJ;
    out[oo*NPOS + i*NJ + j]=res[oo*101+j];
  }
}

// pass C: in-place BN2 affine on d_out
__global__ void k_passC(float* out, const float* ws){
  int idx=blockIdx.x*256+threadIdx.x;
  int stride=gridDim.x*256;
  const int n4=H2C*NPOS/4;
  float4* o4=(float4*)out;
  for(int e=idx;e<n4;e+=stride){
    int o2=e/(NPOS/4);
    float sc=ws[W_SC2+o2], sh=ws[W_SC2+H2C+o2];
    float4 v=o4[e];
    v.x=v.x*sc+sh; v.y=v.y*sc+sh; v.z=v.z*sc+sh; v.w=v.w*sc+sh;
    o4[e]=v;
  }
}

extern "C" void kernel_launch(void* const* d_in, const int* in_sizes, int n_in,
                              void* d_out, int out_size, void* d_ws, size_t ws_size,
                              hipStream_t stream){
  const float* z0     =(const float*)d_in[0];
  const float* z1     =(const float*)d_in[1];
  const float* we1    =(const float*)d_in[2];
  const float* we2    =(const float*)d_in[3];
  const float* we3    =(const float*)d_in[4];
  const float* we4    =(const float*)d_in[5];
  const float* we5    =(const float*)d_in[6];
  const float* conv_w =(const float*)d_in[7];
  const float* conv_b =(const float*)d_in[8];
  const float* bn_g   =(const float*)d_in[9];
  const float* bn_b   =(const float*)d_in[10];
  const float* conv2_w=(const float*)d_in[11];
  const float* conv2_b=(const float*)d_in[12];
  const float* bn2_g  =(const float*)d_in[13];
  const float* bn2_b  =(const float*)d_in[14];
  const int* cdrH=(const int*)d_in[15];
  const int* cdrL=(const int*)d_in[16];
  const int* notH=(const int*)d_in[17];
  const int* notL=(const int*)d_in[18];
  int nCdrH=in_sizes[15], nCdrL=in_sizes[16], nNotH=in_sizes[17], nNotL=in_sizes[18];
  float* ws=(float*)d_ws;
  float* out=(float*)d_out;

  hipLaunchKernelGGL(k_zero,     dim3(1),     dim3(256),0,stream, ws);
  hipLaunchKernelGGL(k_colmeans, dim3(DD),    dim3(256),0,stream, z0,z1,ws);
  hipLaunchKernelGGL(k_pairmeans,dim3(DD),    dim3(256),0,stream, z1,cdrH,notH,cdrL,notL,
                     nCdrH,nNotH,nCdrL,nNotL,ws);
  hipLaunchKernelGGL(k_scales,   dim3(1),     dim3(256),0,stream, we1,we2,we3,we4,we5,ws);
  hipLaunchKernelGGL(k_a0,       dim3(DD*16), dim3(256),0,stream, z0,ws);
  hipLaunchKernelGGL(k_passA,    dim3(LL0),   dim3(256),0,stream, ws,conv_w,conv_b, ws+W_BN1S);
  hipLaunchKernelGGL(k_bnparams, dim3(1),     dim3(256),0,stream, ws,bn_g,bn_b, HC, W_BN1S, W_SC1);
  hipLaunchKernelGGL(k_passB,    dim3(LL0),   dim3(256),0,stream, ws,conv_w,conv_b,conv2_w,conv2_b,
                     out, ws+W_BN2S);
  hipLaunchKernelGGL(k_bnparams, dim3(1),     dim3(256),0,stream, ws,bn2_g,bn2_b, H2C, W_BN2S, W_SC2);
  hipLaunchKernelGGL(k_passC,    dim3(2048),  dim3(256),0,stream, out, ws);
}

// Round 2
// 1365.765 us; speedup vs baseline: 2.1963x; 2.1963x over previous
//
#include <hip/hip_runtime.h>
#include <math.h>

#define DD   46
#define LL0  4000
#define LL1  600
#define CATV 250
#define NC   50
#define NJ   100
#define HC   256
#define H2C  128
#define NPOS (LL0*NJ)
#define EPSV 1e-5f
#define CH   16
#define NCHUNK 7
#define C1PAD 260

// ---- workspace float offsets ----
#define W_MEAN0   0
#define W_MEANH   64
#define W_MEANL   128
#define W_RM4     192
#define W_RM5     256
#define W_S1      320
#define W_HBAR    384
#define W_RAWMH   448
#define W_RAWML   (W_RAWMH+2304)
#define W_H       (W_RAWML+2304)
#define W_L       (W_H+2304)
#define W_BN1S    (W_L+2304)          // 256 sum, then 256 sumsq
#define W_SC1     (W_BN1S+512)        // 256 scale, then 256 shift
#define W_BN2S    (W_SC1+512)         // 128 sum, 128 sumsq
#define W_SC2     (W_BN2S+256)        // 128 scale, 128 shift
#define W_A0      11264
#define W_LDIF    (W_A0+DD*LL0)
#define W_LMUL    (W_LDIF+DD*LL0)
#define W_TOTAL   (W_LMUL+DD*LL0)     // = 563264
#define W_W1T     563264              // [92][256] = 23552
#define W_W2P     586816              // [64][128][4] = 32768

__device__ __forceinline__ float sigf(float x){ return 1.0f/(1.0f+__expf(-x)); }

__device__ float blockReduceSum(float v, float* sm){
  int tid=threadIdx.x;
  sm[tid]=v; __syncthreads();
  for(int s=128;s>0;s>>=1){ if(tid<s) sm[tid]+=sm[tid+s]; __syncthreads(); }
  float r=sm[0]; __syncthreads();
  return r;
}

// zero BN stat + param region
__global__ void k_zero(float* ws){
  for(int e=threadIdx.x;e<1536;e+=256) ws[W_BN1S+e]=0.f;
}

// transpose/pack weights: W1t[k][o] ; W2p[kq][o][q]
__global__ void k_prep(const float* __restrict__ conv_w, const float* __restrict__ conv2_w,
                       float* __restrict__ ws){
  int t = blockIdx.x*256 + threadIdx.x;
  if(t < 92*HC){ int k=t/HC, o=t-k*HC; ws[W_W1T+t]=conv_w[o*92+k]; }
  if(t < 64*H2C*4){ int kq=t>>9, o=(t>>2)&127, q=t&3; ws[W_W2P+t]=conv2_w[o*HC+kq*4+q]; }
}

// per-channel means of z0, z1H, z1L (pre-ECA inputs)
__global__ void k_colmeans(const float* z0, const float* z1, float* ws){
  __shared__ float sm[256];
  int d=blockIdx.x, tid=threadIdx.x;
  float s0=0.f; for(int i=tid;i<LL0;i+=256) s0+=z0[i*DD+d];
  float sH=0.f; for(int k=tid;k<CATV;k+=256) sH+=z1[k*DD+d];
  float sL=0.f; for(int k=CATV+tid;k<LL1;k+=256) sL+=z1[k*DD+d];
  float r0=blockReduceSum(s0,sm);
  float rH=blockReduceSum(sH,sm);
  float rL=blockReduceSum(sL,sm);
  if(tid==0){
    ws[W_MEAN0+d]=r0/(float)LL0;
    ws[W_MEANH+d]=rH/(float)CATV;
    ws[W_MEANL+d]=rL/(float)(LL1-CATV);
  }
}

// raw pair-difference means (pre-scale)
__global__ void k_pairmeans(const float* z1, const int* cdrH, const int* notH,
                            const int* cdrL, const int* notL,
                            int nCdrH,int nNotH,int nCdrL,int nNotL, float* ws){
  __shared__ float v[LL1];
  __shared__ float sm[256];
  int d=blockIdx.x, tid=threadIdx.x;
  for(int k=tid;k<LL1;k+=256) v[k]=z1[k*DD+d];
  __syncthreads();
  float partH=0.f, partL=0.f;
  for(int i=tid;i<nCdrH;i+=256){
    float c=v[cdrH[i]]; float s=0.f;
    for(int j=0;j<nNotH;j++) s+=fabsf(c-v[notH[j]]);
    s/= (float)nNotH;
    ws[W_RAWMH+d*NC+i]=s; partH+=s;
  }
  for(int i=tid;i<nCdrL;i+=256){
    float c=v[CATV+cdrL[i]]; float s=0.f;
    for(int j=0;j<nNotL;j++) s+=fabsf(c-v[CATV+notL[j]]);
    s/= (float)nNotL;
    ws[W_RAWML+d*NC+i]=s; partL+=s;
  }
  float rH=blockReduceSum(partH,sm);
  float rL=blockReduceSum(partL,sm);
  if(tid==0){ ws[W_RM4+d]=rH/(float)nCdrH; ws[W_RM5+d]=rL/(float)nCdrL; }
}

__device__ __forceinline__ float conv3(const float* a, int d, const float* w){
  float acc = w[1]*a[d];
  if(d>0)    acc += w[0]*a[d-1];
  if(d<DD-1) acc += w[2]*a[d+1];
  return acc;
}

// all sigmoid scales + final h, l, hbar
__global__ void k_scales(const float* w1,const float* w2,const float* w3,
                         const float* w4,const float* w5, float* ws){
  __shared__ float m0[DD], mH[DD], mL[DD];
  __shared__ float s1s[DD],s2s[DD],s3s[DD],s4s[DD],s5s[DD],y4[DD],y5[DD];
  int tid=threadIdx.x;
  if(tid<DD){ m0[tid]=ws[W_MEAN0+tid]; mH[tid]=ws[W_MEANH+tid]; mL[tid]=ws[W_MEANL+tid]; }
  __syncthreads();
  if(tid<DD){
    s1s[tid]=sigf(conv3(m0,tid,w1));
    s2s[tid]=sigf(conv3(mH,tid,w2));
    s3s[tid]=sigf(conv3(mL,tid,w3));
  }
  __syncthreads();
  if(tid<DD){ y4[tid]=s2s[tid]*ws[W_RM4+tid]; y5[tid]=s3s[tid]*ws[W_RM5+tid]; }
  __syncthreads();
  if(tid<DD){
    s4s[tid]=sigf(conv3(y4,tid,w4));
    s5s[tid]=sigf(conv3(y5,tid,w5));
    ws[W_S1+tid]=s1s[tid];
  }
  __syncthreads();
  for(int e=tid;e<DD*NC;e+=256){
    int d=e/NC;
    ws[W_H+e]=s4s[d]*s2s[d]*ws[W_RAWMH+e];
    ws[W_L+e]=s5s[d]*s3s[d]*ws[W_RAWML+e];
  }
  __syncthreads();
  if(tid<DD){
    float s=0.f;
    for(int j=0;j<NC;j++) s+=ws[W_H+tid*NC+j];
    ws[W_HBAR+tid]=s/(float)NC;
  }
}

// a0 = s1*z0 ; Ldif = mean_j |a0-h_j| ; Lmul = a0*hbar
__global__ void k_a0(const float* z0, float* ws){
  __shared__ float hs[NC];
  int b=blockIdx.x; int d=b>>4; int i=((b&15)<<8)+threadIdx.x;
  if(threadIdx.x<NC) hs[threadIdx.x]=ws[W_H+d*NC+threadIdx.x];
  __syncthreads();
  if(i<LL0){
    float a=ws[W_S1+d]*z0[i*DD+d];
    float s=0.f;
    #pragma unroll
    for(int j=0;j<NC;j++) s+=fabsf(a-hs[j]);
    ws[W_A0 +d*LL0+i]=a;
    ws[W_LDIF+d*LL0+i]=s*(1.0f/(float)NC);
    ws[W_LMUL+d*LL0+i]=a*ws[W_HBAR+d];
  }
}

// build one j-chunk of the feature matrix, transposed: xcT[92][CH]
__device__ __forceinline__ void build_chunk(float* xcT, const float* __restrict__ ws,
                                            const float* av, const float* dv, const float* mv,
                                            int j0, int tid){
  for(int e=tid;e<92*CH;e+=256){
    int c=e>>4, jj=e&15, j=j0+jj;
    int d=(c<DD)?c:c-DD;
    float x=0.f;
    if(j<NJ){
      if(j<NC){
        float hv=ws[W_H+d*NC+j];
        x=(c<DD)?fabsf(av[d]-hv):av[d]*hv;
      }else{
        float lv=ws[W_L+d*NC+(j-NC)];
        x=(c<DD)?fabsf(dv[d]-lv):fabsf(mv[d]-lv);
      }
    }
    xcT[e]=x;
  }
}

// conv1 register-tiled: acc[oq][jq] over K=92, a-frag LDS broadcast, b-frag global W1t
__device__ __forceinline__ void conv1_tile(const float* xcT, const float* __restrict__ W1t,
                                           int tx, int ty, float acc[4][4]){
  #pragma unroll
  for(int a=0;a<4;a++)
    #pragma unroll
    for(int b=0;b<4;b++) acc[a][b]=0.f;
  #pragma unroll 4
  for(int k=0;k<92;k++){
    float4 af = *(const float4*)&xcT[k*CH + ty*4];
    float4 bf = *(const float4*)&W1t[k*HC + tx*4];
    acc[0][0]+=bf.x*af.x; acc[0][1]+=bf.x*af.y; acc[0][2]+=bf.x*af.z; acc[0][3]+=bf.x*af.w;
    acc[1][0]+=bf.y*af.x; acc[1][1]+=bf.y*af.y; acc[1][2]+=bf.y*af.z; acc[1][3]+=bf.y*af.w;
    acc[2][0]+=bf.z*af.x; acc[2][1]+=bf.z*af.y; acc[2][2]+=bf.z*af.z; acc[2][3]+=bf.z*af.w;
    acc[3][0]+=bf.w*af.x; acc[3][1]+=bf.w*af.y; acc[3][2]+=bf.w*af.z; acc[3][3]+=bf.w*af.w;
  }
}

// pass A: conv1 + relu, accumulate BN1 sum/sumsq
__global__ __launch_bounds__(256) void k_passA(const float* __restrict__ ws,
                                               const float* __restrict__ conv_b,
                                               float* __restrict__ bnsum){
  __shared__ float xcT[92*CH];
  __shared__ float av[DD], dv[DD], mv[DD];
  __shared__ float pr[2560];
  const float* __restrict__ W1t = ws + W_W1T;
  const int i=blockIdx.x, tid=threadIdx.x;
  const int tx=tid&63, ty=tid>>6;
  if(tid<DD){
    av[tid]=ws[W_A0 +tid*LL0+i];
    dv[tid]=ws[W_LDIF+tid*LL0+i];
    mv[tid]=ws[W_LMUL+tid*LL0+i];
  }
  float b4[4];
  #pragma unroll
  for(int oq=0;oq<4;oq++) b4[oq]=conv_b[tx*4+oq];
  float s1[4]={0,0,0,0}, q1[4]={0,0,0,0};
  for(int jc=0;jc<NCHUNK;jc++){
    __syncthreads();
    build_chunk(xcT,ws,av,dv,mv,jc*CH,tid);
    __syncthreads();
    float acc[4][4];
    conv1_tile(xcT,W1t,tx,ty,acc);
    #pragma unroll
    for(int jq=0;jq<4;jq++){
      if(jc*CH + ty*4 + jq < NJ){
        #pragma unroll
        for(int oq=0;oq<4;oq++){
          float r=fmaxf(acc[oq][jq]+b4[oq],0.f);
          s1[oq]+=r; q1[oq]+=r*r;
        }
      }
    }
  }
  __syncthreads();
  #pragma unroll
  for(int oq=0;oq<4;oq++){
    pr[(tx*4+oq)*5+ty]      = s1[oq];
    pr[1280+(tx*4+oq)*5+ty] = q1[oq];
  }
  __syncthreads();
  {
    int o=tid;
    float s=pr[o*5+0]+pr[o*5+1]+pr[o*5+2]+pr[o*5+3];
    float q=pr[1280+o*5+0]+pr[1280+o*5+1]+pr[1280+o*5+2]+pr[1280+o*5+3];
    atomicAdd(&bnsum[o],s); atomicAdd(&bnsum[HC+o],q);
  }
}

// BN params: scale = g*rsqrt(var+eps), shift = b - mu*scale
__global__ void k_bnparams(float* ws, const float* g, const float* b,
                           int nch, int sumoff, int scoff){
  int o=threadIdx.x;
  if(o<nch){
    float mu =ws[sumoff+o]    *(1.0f/(float)NPOS);
    float ex2=ws[sumoff+nch+o]*(1.0f/(float)NPOS);
    float var=ex2-mu*mu; if(var<0.f) var=0.f;
    float sc=g[o]*rsqrtf(var+EPSV);
    ws[scoff+o]=sc;
    ws[scoff+nch+o]=b[o]-mu*sc;
  }
}

// pass B: conv1 recompute + BN1 + conv2 + relu; BN2 stats; write pre-BN2 to out
__global__ __launch_bounds__(256) void k_passB(const float* __restrict__ ws,
      const float* __restrict__ conv_b, const float* __restrict__ conv2_b,
      float* __restrict__ out, float* __restrict__ bn2sum){
  __shared__ float xcT[92*CH];
  __shared__ float c1s[CH][C1PAD];
  __shared__ float av[DD], dv[DD], mv[DD];
  const float* __restrict__ W1t = ws + W_W1T;
  const float* __restrict__ W2p = ws + W_W2P;
  const int i=blockIdx.x, tid=threadIdx.x;
  const int tx=tid&63, ty=tid>>6;
  if(tid<DD){
    av[tid]=ws[W_A0 +tid*LL0+i];
    dv[tid]=ws[W_LDIF+tid*LL0+i];
    mv[tid]=ws[W_LMUL+tid*LL0+i];
  }
  float b4[4], sc4[4], sh4[4];
  #pragma unroll
  for(int oq=0;oq<4;oq++){
    b4[oq] =conv_b[tx*4+oq];
    sc4[oq]=ws[W_SC1+tx*4+oq];
    sh4[oq]=ws[W_SC1+HC+tx*4+oq];
  }
  float bias2[2]={conv2_b[tx*2],conv2_b[tx*2+1]};
  float s2[2]={0,0}, q2[2]={0,0};
  for(int jc=0;jc<NCHUNK;jc++){
    __syncthreads();
    build_chunk(xcT,ws,av,dv,mv,jc*CH,tid);
    __syncthreads();
    float acc[4][4];
    conv1_tile(xcT,W1t,tx,ty,acc);
    // relu + BN1 affine, store own-wave rows of c1s (contiguous b128, conflict-free)
    #pragma unroll
    for(int jq=0;jq<4;jq++){
      float4 v;
      v.x=fmaxf(acc[0][jq]+b4[0],0.f)*sc4[0]+sh4[0];
      v.y=fmaxf(acc[1][jq]+b4[1],0.f)*sc4[1]+sh4[1];
      v.z=fmaxf(acc[2][jq]+b4[2],0.f)*sc4[2]+sh4[2];
      v.w=fmaxf(acc[3][jq]+b4[3],0.f)*sc4[3]+sh4[3];
      *(float4*)&c1s[ty*4+jq][tx*4]=v;
    }
    // conv2: reads only this wave's 4 rows of c1s (no barrier needed)
    float a2[2][4];
    #pragma unroll
    for(int a=0;a<2;a++)
      #pragma unroll
      for(int b=0;b<4;b++) a2[a][b]=0.f;
    #pragma unroll 2
    for(int kq=0;kq<64;kq++){
      float4 va0=*(const float4*)&c1s[ty*4+0][kq*4];
      float4 va1=*(const float4*)&c1s[ty*4+1][kq*4];
      float4 va2=*(const float4*)&c1s[ty*4+2][kq*4];
      float4 va3=*(const float4*)&c1s[ty*4+3][kq*4];
      float4 w0=*(const float4*)&W2p[kq*512 + tx*8];
      float4 w1=*(const float4*)&W2p[kq*512 + tx*8 + 4];
      a2[0][0]+=w0.x*va0.x+w0.y*va0.y+w0.z*va0.z+w0.w*va0.w;
      a2[0][1]+=w0.x*va1.x+w0.y*va1.y+w0.z*va1.z+w0.w*va1.w;
      a2[0][2]+=w0.x*va2.x+w0.y*va2.y+w0.z*va2.z+w0.w*va2.w;
      a2[0][3]+=w0.x*va3.x+w0.y*va3.y+w0.z*va3.z+w0.w*va3.w;
      a2[1][0]+=w1.x*va0.x+w1.y*va0.y+w1.z*va0.z+w1.w*va0.w;
      a2[1][1]+=w1.x*va1.x+w1.y*va1.y+w1.z*va1.z+w1.w*va1.w;
      a2[1][2]+=w1.x*va2.x+w1.y*va2.y+w1.z*va2.z+w1.w*va2.w;
      a2[1][3]+=w1.x*va3.x+w1.y*va3.y+w1.z*va3.z+w1.w*va3.w;
    }
    // relu + BN2 stats + write pre-BN2
    int jbase=jc*CH+ty*4;
    #pragma unroll
    for(int o2q=0;o2q<2;o2q++){
      float r0=fmaxf(a2[o2q][0]+bias2[o2q],0.f);
      float r1=fmaxf(a2[o2q][1]+bias2[o2q],0.f);
      float r2=fmaxf(a2[o2q][2]+bias2[o2q],0.f);
      float r3=fmaxf(a2[o2q][3]+bias2[o2q],0.f);
      float* op=out+(size_t)(tx*2+o2q)*NPOS + i*NJ + jbase;
      if(jbase+3<NJ){
        s2[o2q]+=r0+r1+r2+r3;
        q2[o2q]+=r0*r0+r1*r1+r2*r2+r3*r3;
        float4 v; v.x=r0; v.y=r1; v.z=r2; v.w=r3;
        *(float4*)op=v;
      }else{
        if(jbase+0<NJ){ s2[o2q]+=r0; q2[o2q]+=r0*r0; op[0]=r0; }
        if(jbase+1<NJ){ s2[o2q]+=r1; q2[o2q]+=r1*r1; op[1]=r1; }
        if(jbase+2<NJ){ s2[o2q]+=r2; q2[o2q]+=r2*r2; op[2]=r2; }
        if(jbase+3<NJ){ s2[o2q]+=r3; q2[o2q]+=r3*r3; op[3]=r3; }
      }
    }
  }
  // BN2 partial reduce (reuse xcT as scratch: need 1280 floats)
  __syncthreads();
  float* red=xcT;
  #pragma unroll
  for(int o2q=0;o2q<2;o2q++){
    red[(tx*2+o2q)*5+ty]     =s2[o2q];
    red[640+(tx*2+o2q)*5+ty] =q2[o2q];
  }
  __syncthreads();
  if(tid<H2C){
    int o=tid;
    float s=red[o*5+0]+red[o*5+1]+red[o*5+2]+red[o*5+3];
    float q=red[640+o*5+0]+red[640+o*5+1]+red[640+o*5+2]+red[640+o*5+3];
    atomicAdd(&bn2sum[o],s); atomicAdd(&bn2sum[H2C+o],q);
  }
}

// pass C: in-place BN2 affine on d_out
__global__ void k_passC(float* out, const float* ws){
  int idx=blockIdx.x*256+threadIdx.x;
  int stride=gridDim.x*256;
  const int n4=H2C*NPOS/4;
  float4* o4=(float4*)out;
  for(int e=idx;e<n4;e+=stride){
    int o2=e/(NPOS/4);
    float sc=ws[W_SC2+o2], sh=ws[W_SC2+H2C+o2];
    float4 v=o4[e];
    v.x=v.x*sc+sh; v.y=v.y*sc+sh; v.z=v.z*sc+sh; v.w=v.w*sc+sh;
    o4[e]=v;
  }
}

extern "C" void kernel_launch(void* const* d_in, const int* in_sizes, int n_in,
                              void* d_out, int out_size, void* d_ws, size_t ws_size,
                              hipStream_t stream){
  const float* z0     =(const float*)d_in[0];
  const float* z1     =(const float*)d_in[1];
  const float* we1    =(const float*)d_in[2];
  const float* we2    =(const float*)d_in[3];
  const float* we3    =(const float*)d_in[4];
  const float* we4    =(const float*)d_in[5];
  const float* we5    =(const float*)d_in[6];
  const float* conv_w =(const float*)d_in[7];
  const float* conv_b =(const float*)d_in[8];
  const float* bn_g   =(const float*)d_in[9];
  const float* bn_b   =(const float*)d_in[10];
  const float* conv2_w=(const float*)d_in[11];
  const float* conv2_b=(const float*)d_in[12];
  const float* bn2_g  =(const float*)d_in[13];
  const float* bn2_b  =(const float*)d_in[14];
  const int* cdrH=(const int*)d_in[15];
  const int* cdrL=(const int*)d_in[16];
  const int* notH=(const int*)d_in[17];
  const int* notL=(const int*)d_in[18];
  int nCdrH=in_sizes[15], nCdrL=in_sizes[16], nNotH=in_sizes[17], nNotL=in_sizes[18];
  float* ws=(float*)d_ws;
  float* out=(float*)d_out;

  hipLaunchKernelGGL(k_zero,     dim3(1),     dim3(256),0,stream, ws);
  hipLaunchKernelGGL(k_prep,     dim3(128),   dim3(256),0,stream, conv_w,conv2_w,ws);
  hipLaunchKernelGGL(k_colmeans, dim3(DD),    dim3(256),0,stream, z0,z1,ws);
  hipLaunchKernelGGL(k_pairmeans,dim3(DD),    dim3(256),0,stream, z1,cdrH,notH,cdrL,notL,
                     nCdrH,nNotH,nCdrL,nNotL,ws);
  hipLaunchKernelGGL(k_scales,   dim3(1),     dim3(256),0,stream, we1,we2,we3,we4,we5,ws);
  hipLaunchKernelGGL(k_a0,       dim3(DD*16), dim3(256),0,stream, z0,ws);
  hipLaunchKernelGGL(k_passA,    dim3(LL0),   dim3(256),0,stream, ws,conv_b, ws+W_BN1S);
  hipLaunchKernelGGL(k_bnparams, dim3(1),     dim3(256),0,stream, ws,bn_g,bn_b, HC, W_BN1S, W_SC1);
  hipLaunchKernelGGL(k_passB,    dim3(LL0),   dim3(256),0,stream, ws,conv_b,conv2_b,
                     out, ws+W_BN2S);
  hipLaunchKernelGGL(k_bnparams, dim3(1),     dim3(256),0,stream, ws,bn2_g,bn2_b, H2C, W_BN2S, W_SC2);
  hipLaunchKernelGGL(k_passC,    dim3(2048),  dim3(256),0,stream, out, ws);
}

// Round 3
// 464.944 us; speedup vs baseline: 6.4515x; 2.9375x over previous
//
#include <hip/hip_runtime.h>
#include <math.h>

#define DD   46
#define LL0  4000
#define LL1  600
#define CATV 250
#define NC   50
#define NJ   100
#define HC   256
#define H2C  128
#define NPOS (LL0*NJ)
#define EPSV 1e-5f
#define NT   64
#define XROW 104
#define C1ROW 264

// ---- workspace float offsets ----
#define W_MEAN0   0
#define W_MEANH   64
#define W_MEANL   128
#define W_RM4     192
#define W_RM5     256
#define W_S1      320
#define W_HBAR    384
#define W_RAWMH   448
#define W_RAWML   (W_RAWMH+2304)
#define W_H       (W_RAWML+2304)
#define W_L       (W_H+2304)
#define W_BN1S    (W_L+2304)          // 256 sum, then 256 sumsq
#define W_SC1     (W_BN1S+512)        // 256 scale, then 256 shift
#define W_BN2S    (W_SC1+512)         // 128 sum, 128 sumsq
#define W_SC2     (W_BN2S+256)        // 128 scale, 128 shift
#define W_A0      11264
#define W_LDIF    (W_A0+DD*LL0)
#define W_LMUL    (W_LDIF+DD*LL0)
#define W_TOTAL   (W_LMUL+DD*LL0)     // = 563264
#define W_W1BF    563264              // 256*96 ushort = 12288 floats
#define W_W2BF    575552              // 128*256 ushort = 16384 floats
#define W_BIAS2   591936              // 128 floats

typedef __attribute__((ext_vector_type(8))) short bf8;
typedef __attribute__((ext_vector_type(4))) float f32x4;

__device__ __forceinline__ float sigf(float x){ return 1.0f/(1.0f+__expf(-x)); }

__device__ __forceinline__ unsigned short f2bf(float f){
  unsigned u = __float_as_uint(f);
  return (unsigned short)((u + 0x7FFFu + ((u>>16)&1u)) >> 16);
}
__device__ __forceinline__ unsigned pk2bf(float a, float b){
  return ((unsigned)f2bf(b)<<16) | (unsigned)f2bf(a);
}

__device__ float blockReduceSum(float v, float* sm){
  int tid=threadIdx.x;
  sm[tid]=v; __syncthreads();
  for(int s=128;s>0;s>>=1){ if(tid<s) sm[tid]+=sm[tid+s]; __syncthreads(); }
  float r=sm[0]; __syncthreads();
  return r;
}

// zero BN stat + param region
__global__ void k_zero(float* ws){
  for(int e=threadIdx.x;e<1536;e+=256) ws[W_BN1S+e]=0.f;
}

// W1 -> bf16, K padded 92->96
__global__ void k_prep(const float* __restrict__ conv_w, float* __restrict__ ws){
  int t=blockIdx.x*256+threadIdx.x;
  if(t<HC*96){
    int o=t/96, k=t-o*96;
    ((unsigned short*)(ws+W_W1BF))[t] = (k<92)? f2bf(conv_w[o*92+k]) : (unsigned short)0;
  }
}

// W2' = W2*sc1 (bf16), bias2' = b2 + sum_k W2[o2,k]*sh1[k]  (after BN1 params)
__global__ void k_prep2(const float* __restrict__ conv2_w, const float* __restrict__ conv2_b,
                        float* __restrict__ ws){
  __shared__ float sm[256];
  int o2=blockIdx.x, t=threadIdx.x;
  float wv=conv2_w[o2*HC+t];
  float sc=ws[W_SC1+t], sh=ws[W_SC1+HC+t];
  ((unsigned short*)(ws+W_W2BF))[o2*HC+t]=f2bf(wv*sc);
  float r=blockReduceSum(wv*sh,sm);
  if(t==0) ws[W_BIAS2+o2]=conv2_b[o2]+r;
}

// per-channel means of z0, z1H, z1L (pre-ECA inputs)
__global__ void k_colmeans(const float* z0, const float* z1, float* ws){
  __shared__ float sm[256];
  int d=blockIdx.x, tid=threadIdx.x;
  float s0=0.f; for(int i=tid;i<LL0;i+=256) s0+=z0[i*DD+d];
  float sH=0.f; for(int k=tid;k<CATV;k+=256) sH+=z1[k*DD+d];
  float sL=0.f; for(int k=CATV+tid;k<LL1;k+=256) sL+=z1[k*DD+d];
  float r0=blockReduceSum(s0,sm);
  float rH=blockReduceSum(sH,sm);
  float rL=blockReduceSum(sL,sm);
  if(tid==0){
    ws[W_MEAN0+d]=r0/(float)LL0;
    ws[W_MEANH+d]=rH/(float)CATV;
    ws[W_MEANL+d]=rL/(float)(LL1-CATV);
  }
}

// raw pair-difference means (pre-scale)
__global__ void k_pairmeans(const float* z1, const int* cdrH, const int* notH,
                            const int* cdrL, const int* notL,
                            int nCdrH,int nNotH,int nCdrL,int nNotL, float* ws){
  __shared__ float v[LL1];
  __shared__ float sm[256];
  int d=blockIdx.x, tid=threadIdx.x;
  for(int k=tid;k<LL1;k+=256) v[k]=z1[k*DD+d];
  __syncthreads();
  float partH=0.f, partL=0.f;
  for(int i=tid;i<nCdrH;i+=256){
    float c=v[cdrH[i]]; float s=0.f;
    for(int j=0;j<nNotH;j++) s+=fabsf(c-v[notH[j]]);
    s/= (float)nNotH;
    ws[W_RAWMH+d*NC+i]=s; partH+=s;
  }
  for(int i=tid;i<nCdrL;i+=256){
    float c=v[CATV+cdrL[i]]; float s=0.f;
    for(int j=0;j<nNotL;j++) s+=fabsf(c-v[CATV+notL[j]]);
    s/= (float)nNotL;
    ws[W_RAWML+d*NC+i]=s; partL+=s;
  }
  float rH=blockReduceSum(partH,sm);
  float rL=blockReduceSum(partL,sm);
  if(tid==0){ ws[W_RM4+d]=rH/(float)nCdrH; ws[W_RM5+d]=rL/(float)nCdrL; }
}

__device__ __forceinline__ float conv3(const float* a, int d, const float* w){
  float acc = w[1]*a[d];
  if(d>0)    acc += w[0]*a[d-1];
  if(d<DD-1) acc += w[2]*a[d+1];
  return acc;
}

// all sigmoid scales + final h, l, hbar
__global__ void k_scales(const float* w1,const float* w2,const float* w3,
                         const float* w4,const float* w5, float* ws){
  __shared__ float m0[DD], mH[DD], mL[DD];
  __shared__ float s1s[DD],s2s[DD],s3s[DD],s4s[DD],s5s[DD],y4[DD],y5[DD];
  int tid=threadIdx.x;
  if(tid<DD){ m0[tid]=ws[W_MEAN0+tid]; mH[tid]=ws[W_MEANH+tid]; mL[tid]=ws[W_MEANL+tid]; }
  __syncthreads();
  if(tid<DD){
    s1s[tid]=sigf(conv3(m0,tid,w1));
    s2s[tid]=sigf(conv3(mH,tid,w2));
    s3s[tid]=sigf(conv3(mL,tid,w3));
  }
  __syncthreads();
  if(tid<DD){ y4[tid]=s2s[tid]*ws[W_RM4+tid]; y5[tid]=s3s[tid]*ws[W_RM5+tid]; }
  __syncthreads();
  if(tid<DD){
    s4s[tid]=sigf(conv3(y4,tid,w4));
    s5s[tid]=sigf(conv3(y5,tid,w5));
    ws[W_S1+tid]=s1s[tid];
  }
  __syncthreads();
  for(int e=tid;e<DD*NC;e+=256){
    int d=e/NC;
    ws[W_H+e]=s4s[d]*s2s[d]*ws[W_RAWMH+e];
    ws[W_L+e]=s5s[d]*s3s[d]*ws[W_RAWML+e];
  }
  __syncthreads();
  if(tid<DD){
    float s=0.f;
    for(int j=0;j<NC;j++) s+=ws[W_H+tid*NC+j];
    ws[W_HBAR+tid]=s/(float)NC;
  }
}

// a0 = s1*z0 ; Ldif = mean_j |a0-h_j| ; Lmul = a0*hbar
__global__ void k_a0(const float* z0, float* ws){
  __shared__ float hs[NC];
  int b=blockIdx.x; int d=b>>4; int i=((b&15)<<8)+threadIdx.x;
  if(threadIdx.x<NC) hs[threadIdx.x]=ws[W_H+d*NC+threadIdx.x];
  __syncthreads();
  if(i<LL0){
    float a=ws[W_S1+d]*z0[i*DD+d];
    float s=0.f;
    #pragma unroll
    for(int j=0;j<NC;j++) s+=fabsf(a-hs[j]);
    ws[W_A0 +d*LL0+i]=a;
    ws[W_LDIF+d*LL0+i]=s*(1.0f/(float)NC);
    ws[W_LMUL+d*LL0+i]=a*ws[W_HBAR+d];
  }
}

// stage h/l + per-i vectors to LDS, build X[NT][96] bf16 tile (rows padded to XROW)
__device__ __forceinline__ void stage_build(unsigned short* Xl, float* hlds, float* aw,
                                            const float* __restrict__ ws, int n0, int tid){
  for(int t=tid;t<2300;t+=256) hlds[t]      = ws[W_H+t];
  for(int t=tid;t<2300;t+=256) hlds[2300+t] = ws[W_L+t];
  int i0=n0/100;
  if(tid<92){
    int ii=tid/46, dd=tid-46*(tid/46);
    int i=i0+ii; if(i>LL0-1) i=LL0-1;
    aw[tid]     = ws[W_A0  + dd*LL0 + i];
    aw[92+tid]  = ws[W_LDIF+ dd*LL0 + i];
    aw[184+tid] = ws[W_LMUL+ dd*LL0 + i];
  }
  __syncthreads();
  int ib1=(i0+1)*100;
  for(int e=tid;e<NT*46;e+=256){
    int n=e/46, dd=e-n*46;
    int ncol=n0+n;
    int ii=(ncol>=ib1)?1:0;
    int j=ncol-i0*100-ii*100;
    float x1,x2;
    if(j<50){
      float a=aw[ii*46+dd]; float hv=hlds[dd*50+j];
      x1=fabsf(a-hv); x2=a*hv;
    }else{
      float lv=hlds[2300+dd*50+(j-50)];
      x1=fabsf(aw[92+ii*46+dd]-lv);
      x2=fabsf(aw[184+ii*46+dd]-lv);
    }
    Xl[n*XROW+dd]   =f2bf(x1);
    Xl[n*XROW+46+dd]=f2bf(x2);
  }
  for(int e=tid;e<NT*4;e+=256){ int n=e>>2; Xl[n*XROW+92+(e&3)]=0; }
  __syncthreads();
}

// gemm1: acc[tm][tn] = W1[256x96] @ X[96xNT], wave w owns rows [w*64, w*64+64)
__device__ __forceinline__ void gemm1(const unsigned short* __restrict__ W1bf,
                                      const unsigned short* Xl,
                                      int lr,int hi,int mb, f32x4 acc[4][4]){
  #pragma unroll
  for(int tm=0;tm<4;tm++)
    #pragma unroll
    for(int tn=0;tn<4;tn++) acc[tm][tn]=(f32x4){0.f,0.f,0.f,0.f};
  #pragma unroll
  for(int ks=0;ks<3;ks++){
    bf8 a[4],b[4];
    #pragma unroll
    for(int tm=0;tm<4;tm++)
      a[tm]=*(const bf8*)(W1bf + (mb+tm*16+lr)*96 + ks*32 + hi*8);
    #pragma unroll
    for(int tn=0;tn<4;tn++)
      b[tn]=*(const bf8*)(Xl + (tn*16+lr)*XROW + ks*32 + hi*8);
    #pragma unroll
    for(int tm=0;tm<4;tm++)
      #pragma unroll
      for(int tn=0;tn<4;tn++)
        acc[tm][tn]=__builtin_amdgcn_mfma_f32_16x16x32_bf16(a[tm],b[tn],acc[tm][tn],0,0,0);
  }
}

// pass A: gemm1 + relu + BN1 stats only
__global__ __launch_bounds__(256) void k_gemmA(const float* __restrict__ ws,
                                               const float* __restrict__ conv_b,
                                               float* __restrict__ bnsum){
  __shared__ unsigned short Xl[NT*XROW];
  __shared__ float hlds[4600];
  __shared__ float aw[276];
  __shared__ float bnred[512];
  int tid=threadIdx.x, n0=blockIdx.x*NT;
  stage_build(Xl,hlds,aw,ws,n0,tid);
  int l=tid&63, w=tid>>6, lr=l&15, hi=l>>4, mb=w*64;
  const unsigned short* W1bf=(const unsigned short*)(ws+W_W1BF);
  f32x4 acc[4][4];
  gemm1(W1bf,Xl,lr,hi,mb,acc);
  float bb[4][4];
  #pragma unroll
  for(int tm=0;tm<4;tm++)
    #pragma unroll
    for(int r=0;r<4;r++) bb[tm][r]=conv_b[mb+tm*16+hi*4+r];
  float s[4][4], q[4][4];
  #pragma unroll
  for(int tm=0;tm<4;tm++)
    #pragma unroll
    for(int r=0;r<4;r++){ s[tm][r]=0.f; q[tm][r]=0.f; }
  #pragma unroll
  for(int tm=0;tm<4;tm++)
    #pragma unroll
    for(int tn=0;tn<4;tn++)
      #pragma unroll
      for(int r=0;r<4;r++){
        float v=fmaxf(acc[tm][tn][r]+bb[tm][r],0.f);
        s[tm][r]+=v; q[tm][r]+=v*v;
      }
  #pragma unroll
  for(int m=1;m<16;m<<=1)
    #pragma unroll
    for(int tm=0;tm<4;tm++)
      #pragma unroll
      for(int r=0;r<4;r++){
        s[tm][r]+=__shfl_xor(s[tm][r],m);
        q[tm][r]+=__shfl_xor(q[tm][r],m);
      }
  if(lr==0){
    #pragma unroll
    for(int tm=0;tm<4;tm++)
      #pragma unroll
      for(int r=0;r<4;r++){
        int o=mb+tm*16+hi*4+r;
        bnred[o]=s[tm][r]; bnred[256+o]=q[tm][r];
      }
  }
  __syncthreads();
  for(int t=tid;t<512;t+=256) atomicAdd(&bnsum[t],bnred[t]);
}

// BN params: scale = g*rsqrt(var+eps), shift = b - mu*scale
__global__ void k_bnparams(float* ws, const float* g, const float* b,
                           int nch, int sumoff, int scoff){
  int o=threadIdx.x;
  if(o<nch){
    float mu =ws[sumoff+o]    *(1.0f/(float)NPOS);
    float ex2=ws[sumoff+nch+o]*(1.0f/(float)NPOS);
    float var=ex2-mu*mu; if(var<0.f) var=0.f;
    float sc=g[o]*rsqrtf(var+EPSV);
    ws[scoff+o]=sc;
    ws[scoff+nch+o]=b[o]-mu*sc;
  }
}

// pass B: gemm1 -> relu -> bf16 LDS -> gemm2 (BN1 folded into W2') -> relu
//         -> out store + BN2 stats
__global__ __launch_bounds__(256) void k_gemmB(const float* __restrict__ ws,
      const float* __restrict__ conv_b, float* __restrict__ out,
      float* __restrict__ bn2sum){
  __shared__ unsigned short Xl[NT*XROW];
  __shared__ unsigned short C1s[NT*C1ROW];
  __shared__ float hlds[4600];
  __shared__ float aw[276];
  __shared__ float bnred[256];
  int tid=threadIdx.x, n0=blockIdx.x*NT;
  stage_build(Xl,hlds,aw,ws,n0,tid);
  int l=tid&63, w=tid>>6, lr=l&15, hi=l>>4, mb=w*64;
  const unsigned short* W1bf=(const unsigned short*)(ws+W_W1BF);
  f32x4 acc[4][4];
  gemm1(W1bf,Xl,lr,hi,mb,acc);
  float bb[4][4];
  #pragma unroll
  for(int tm=0;tm<4;tm++)
    #pragma unroll
    for(int r=0;r<4;r++) bb[tm][r]=conv_b[mb+tm*16+hi*4+r];
  // relu + pack to C1s[n][o] (bf16, K-major for gemm2 B-frags)
  #pragma unroll
  for(int tm=0;tm<4;tm++)
    #pragma unroll
    for(int tn=0;tn<4;tn++){
      int n=tn*16+lr, ob=mb+tm*16+hi*4;
      float v0=fmaxf(acc[tm][tn][0]+bb[tm][0],0.f);
      float v1=fmaxf(acc[tm][tn][1]+bb[tm][1],0.f);
      float v2=fmaxf(acc[tm][tn][2]+bb[tm][2],0.f);
      float v3=fmaxf(acc[tm][tn][3]+bb[tm][3],0.f);
      uint2 pv; pv.x=pk2bf(v0,v1); pv.y=pk2bf(v2,v3);
      *(uint2*)&C1s[n*C1ROW+ob]=pv;
    }
  __syncthreads();
  // gemm2: W2'[128x256] @ C1[256xNT], wave w owns rows [w*32, w*32+32)
  const unsigned short* W2bf=(const unsigned short*)(ws+W_W2BF);
  const float* bias2=ws+W_BIAS2;
  int mb2=w*32;
  f32x4 acc2[2][4];
  #pragma unroll
  for(int tm=0;tm<2;tm++)
    #pragma unroll
    for(int tn=0;tn<4;tn++) acc2[tm][tn]=(f32x4){0.f,0.f,0.f,0.f};
  #pragma unroll
  for(int ks=0;ks<8;ks++){
    bf8 a[2],b[4];
    #pragma unroll
    for(int tm=0;tm<2;tm++)
      a[tm]=*(const bf8*)(W2bf + (mb2+tm*16+lr)*HC + ks*32 + hi*8);
    #pragma unroll
    for(int tn=0;tn<4;tn++)
      b[tn]=*(const bf8*)(C1s + (tn*16+lr)*C1ROW + ks*32 + hi*8);
    #pragma unroll
    for(int tm=0;tm<2;tm++)
      #pragma unroll
      for(int tn=0;tn<4;tn++)
        acc2[tm][tn]=__builtin_amdgcn_mfma_f32_16x16x32_bf16(a[tm],b[tn],acc2[tm][tn],0,0,0);
  }
  float bb2[2][4], s2[2][4], q2[2][4];
  #pragma unroll
  for(int tm=0;tm<2;tm++)
    #pragma unroll
    for(int r=0;r<4;r++){
      bb2[tm][r]=bias2[mb2+tm*16+hi*4+r];
      s2[tm][r]=0.f; q2[tm][r]=0.f;
    }
  #pragma unroll
  for(int tm=0;tm<2;tm++)
    #pragma unroll
    for(int tn=0;tn<4;tn++)
      #pragma unroll
      for(int r=0;r<4;r++){
        float v=fmaxf(acc2[tm][tn][r]+bb2[tm][r],0.f);
        out[(size_t)(mb2+tm*16+hi*4+r)*(size_t)NPOS + (size_t)(n0+tn*16+lr)]=v;
        s2[tm][r]+=v; q2[tm][r]+=v*v;
      }
  #pragma unroll
  for(int m=1;m<16;m<<=1)
    #pragma unroll
    for(int tm=0;tm<2;tm++)
      #pragma unroll
      for(int r=0;r<4;r++){
        s2[tm][r]+=__shfl_xor(s2[tm][r],m);
        q2[tm][r]+=__shfl_xor(q2[tm][r],m);
      }
  if(lr==0){
    #pragma unroll
    for(int tm=0;tm<2;tm++)
      #pragma unroll
      for(int r=0;r<4;r++){
        int o=mb2+tm*16+hi*4+r;
        bnred[o]=s2[tm][r]; bnred[128+o]=q2[tm][r];
      }
  }
  __syncthreads();
  if(tid<256) atomicAdd(&bn2sum[tid],bnred[tid]);
}

// pass C: in-place BN2 affine on d_out
__global__ void k_passC(float* out, const float* ws){
  int idx=blockIdx.x*256+threadIdx.x;
  int stride=gridDim.x*256;
  const int n4=H2C*NPOS/4;
  float4* o4=(float4*)out;
  for(int e=idx;e<n4;e+=stride){
    int o2=e/(NPOS/4);
    float sc=ws[W_SC2+o2], sh=ws[W_SC2+H2C+o2];
    float4 v=o4[e];
    v.x=v.x*sc+sh; v.y=v.y*sc+sh; v.z=v.z*sc+sh; v.w=v.w*sc+sh;
    o4[e]=v;
  }
}

extern "C" void kernel_launch(void* const* d_in, const int* in_sizes, int n_in,
                              void* d_out, int out_size, void* d_ws, size_t ws_size,
                              hipStream_t stream){
  const float* z0     =(const float*)d_in[0];
  const float* z1     =(const float*)d_in[1];
  const float* we1    =(const float*)d_in[2];
  const float* we2    =(const float*)d_in[3];
  const float* we3    =(const float*)d_in[4];
  const float* we4    =(const float*)d_in[5];
  const float* we5    =(const float*)d_in[6];
  const float* conv_w =(const float*)d_in[7];
  const float* conv_b =(const float*)d_in[8];
  const float* bn_g   =(const float*)d_in[9];
  const float* bn_b   =(const float*)d_in[10];
  const float* conv2_w=(const float*)d_in[11];
  const float* conv2_b=(const float*)d_in[12];
  const float* bn2_g  =(const float*)d_in[13];
  const float* bn2_b  =(const float*)d_in[14];
  const int* cdrH=(const int*)d_in[15];
  const int* cdrL=(const int*)d_in[16];
  const int* notH=(const int*)d_in[17];
  const int* notL=(const int*)d_in[18];
  int nCdrH=in_sizes[15], nCdrL=in_sizes[16], nNotH=in_sizes[17], nNotL=in_sizes[18];
  float* ws=(float*)d_ws;
  float* out=(float*)d_out;
  const int NBLK = NPOS/NT;   // 6250

  hipLaunchKernelGGL(k_zero,     dim3(1),     dim3(256),0,stream, ws);
  hipLaunchKernelGGL(k_prep,     dim3(96),    dim3(256),0,stream, conv_w,ws);
  hipLaunchKernelGGL(k_colmeans, dim3(DD),    dim3(256),0,stream, z0,z1,ws);
  hipLaunchKernelGGL(k_pairmeans,dim3(DD),    dim3(256),0,stream, z1,cdrH,notH,cdrL,notL,
                     nCdrH,nNotH,nCdrL,nNotL,ws);
  hipLaunchKernelGGL(k_scales,   dim3(1),     dim3(256),0,stream, we1,we2,we3,we4,we5,ws);
  hipLaunchKernelGGL(k_a0,       dim3(DD*16), dim3(256),0,stream, z0,ws);
  hipLaunchKernelGGL(k_gemmA,    dim3(NBLK),  dim3(256),0,stream, ws,conv_b, ws+W_BN1S);
  hipLaunchKernelGGL(k_bnparams, dim3(1),     dim3(256),0,stream, ws,bn_g,bn_b, HC, W_BN1S, W_SC1);
  hipLaunchKernelGGL(k_prep2,    dim3(H2C),   dim3(256),0,stream, conv2_w,conv2_b,ws);
  hipLaunchKernelGGL(k_gemmB,    dim3(NBLK),  dim3(256),0,stream, ws,conv_b, out, ws+W_BN2S);
  hipLaunchKernelGGL(k_bnparams, dim3(1),     dim3(256),0,stream, ws,bn2_g,bn2_b, H2C, W_BN2S, W_SC2);
  hipLaunchKernelGGL(k_passC,    dim3(2048),  dim3(256),0,stream, out, ws);
}

// Round 4
// 378.474 us; speedup vs baseline: 7.9255x; 1.2285x over previous
//
#include <hip/hip_runtime.h>
#include <math.h>

#define DD   46
#define LL0  4000
#define LL1  600
#define CATV 250
#define NC   50
#define NJ   100
#define HC   256
#define H2C  128
#define NPOS (LL0*NJ)
#define EPSV 1e-5f
#define NT   64
#define XROW 104
#define C1ROW 264
#define TILES (NPOS/NT)   // 6250
#define GRIDP 768

// ---- workspace float offsets ----
#define W_MEAN0   0
#define W_MEANH   64
#define W_MEANL   128
#define W_RM4     192
#define W_RM5     256
#define W_S1      320
#define W_HBAR    384
#define W_RAWMH   448
#define W_RAWML   (W_RAWMH+2304)
#define W_H       (W_RAWML+2304)
#define W_L       (W_H+2304)
#define W_BN1S    (W_L+2304)          // 256 sum, then 256 sumsq
#define W_SC1     (W_BN1S+512)        // 256 scale, then 256 shift
#define W_BN2S    (W_SC1+512)         // 128 sum, 128 sumsq
#define W_SC2     (W_BN2S+256)        // 128 scale, 128 shift
#define W_A0      11264
#define W_LDIF    (W_A0+DD*LL0)
#define W_LMUL    (W_LDIF+DD*LL0)
#define W_TOTAL   (W_LMUL+DD*LL0)     // = 563264
#define W_W1BF    563264              // 256*96 ushort = 12288 floats
#define W_W2BF    575552              // 128*256 ushort = 16384 floats
#define W_BIAS2   591936              // 128 floats

typedef __attribute__((ext_vector_type(8))) short bf8;
typedef __attribute__((ext_vector_type(4))) float f32x4;

__device__ __forceinline__ float sigf(float x){ return 1.0f/(1.0f+__expf(-x)); }

__device__ __forceinline__ unsigned short f2bf(float f){
  unsigned u = __float_as_uint(f);
  return (unsigned short)((u + 0x7FFFu + ((u>>16)&1u)) >> 16);
}
__device__ __forceinline__ unsigned pk2bf(float a, float b){
  return ((unsigned)f2bf(b)<<16) | (unsigned)f2bf(a);
}

__device__ float blockReduceSum(float v, float* sm){
  int tid=threadIdx.x;
  sm[tid]=v; __syncthreads();
  for(int s=128;s>0;s>>=1){ if(tid<s) sm[tid]+=sm[tid+s]; __syncthreads(); }
  float r=sm[0]; __syncthreads();
  return r;
}

// zero BN stat + param region
__global__ void k_zero(float* ws){
  for(int e=threadIdx.x;e<1536;e+=256) ws[W_BN1S+e]=0.f;
}

// W1 -> bf16, K padded 92->96
__global__ void k_prep(const float* __restrict__ conv_w, float* __restrict__ ws){
  int t=blockIdx.x*256+threadIdx.x;
  if(t<HC*96){
    int o=t/96, k=t-o*96;
    ((unsigned short*)(ws+W_W1BF))[t] = (k<92)? f2bf(conv_w[o*92+k]) : (unsigned short)0;
  }
}

// W2' = W2*sc1 (bf16), bias2' = b2 + sum_k W2[o2,k]*sh1[k]  (after BN1 params)
__global__ void k_prep2(const float* __restrict__ conv2_w, const float* __restrict__ conv2_b,
                        float* __restrict__ ws){
  __shared__ float sm[256];
  int o2=blockIdx.x, t=threadIdx.x;
  float wv=conv2_w[o2*HC+t];
  float sc=ws[W_SC1+t], sh=ws[W_SC1+HC+t];
  ((unsigned short*)(ws+W_W2BF))[o2*HC+t]=f2bf(wv*sc);
  float r=blockReduceSum(wv*sh,sm);
  if(t==0) ws[W_BIAS2+o2]=conv2_b[o2]+r;
}

// per-channel means of z0, z1H, z1L (pre-ECA inputs)
__global__ void k_colmeans(const float* z0, const float* z1, float* ws){
  __shared__ float sm[256];
  int d=blockIdx.x, tid=threadIdx.x;
  float s0=0.f; for(int i=tid;i<LL0;i+=256) s0+=z0[i*DD+d];
  float sH=0.f; for(int k=tid;k<CATV;k+=256) sH+=z1[k*DD+d];
  float sL=0.f; for(int k=CATV+tid;k<LL1;k+=256) sL+=z1[k*DD+d];
  float r0=blockReduceSum(s0,sm);
  float rH=blockReduceSum(sH,sm);
  float rL=blockReduceSum(sL,sm);
  if(tid==0){
    ws[W_MEAN0+d]=r0/(float)LL0;
    ws[W_MEANH+d]=rH/(float)CATV;
    ws[W_MEANL+d]=rL/(float)(LL1-CATV);
  }
}

// raw pair-difference means (pre-scale)
__global__ void k_pairmeans(const float* z1, const int* cdrH, const int* notH,
                            const int* cdrL, const int* notL,
                            int nCdrH,int nNotH,int nCdrL,int nNotL, float* ws){
  __shared__ float v[LL1];
  __shared__ float sm[256];
  int d=blockIdx.x, tid=threadIdx.x;
  for(int k=tid;k<LL1;k+=256) v[k]=z1[k*DD+d];
  __syncthreads();
  float partH=0.f, partL=0.f;
  for(int i=tid;i<nCdrH;i+=256){
    float c=v[cdrH[i]]; float s=0.f;
    for(int j=0;j<nNotH;j++) s+=fabsf(c-v[notH[j]]);
    s/= (float)nNotH;
    ws[W_RAWMH+d*NC+i]=s; partH+=s;
  }
  for(int i=tid;i<nCdrL;i+=256){
    float c=v[CATV+cdrL[i]]; float s=0.f;
    for(int j=0;j<nNotL;j++) s+=fabsf(c-v[CATV+notL[j]]);
    s/= (float)nNotL;
    ws[W_RAWML+d*NC+i]=s; partL+=s;
  }
  float rH=blockReduceSum(partH,sm);
  float rL=blockReduceSum(partL,sm);
  if(tid==0){ ws[W_RM4+d]=rH/(float)nCdrH; ws[W_RM5+d]=rL/(float)nCdrL; }
}

__device__ __forceinline__ float conv3(const float* a, int d, const float* w){
  float acc = w[1]*a[d];
  if(d>0)    acc += w[0]*a[d-1];
  if(d<DD-1) acc += w[2]*a[d+1];
  return acc;
}

// all sigmoid scales + final h, l, hbar
__global__ void k_scales(const float* w1,const float* w2,const float* w3,
                         const float* w4,const float* w5, float* ws){
  __shared__ float m0[DD], mH[DD], mL[DD];
  __shared__ float s1s[DD],s2s[DD],s3s[DD],s4s[DD],s5s[DD],y4[DD],y5[DD];
  int tid=threadIdx.x;
  if(tid<DD){ m0[tid]=ws[W_MEAN0+tid]; mH[tid]=ws[W_MEANH+tid]; mL[tid]=ws[W_MEANL+tid]; }
  __syncthreads();
  if(tid<DD){
    s1s[tid]=sigf(conv3(m0,tid,w1));
    s2s[tid]=sigf(conv3(mH,tid,w2));
    s3s[tid]=sigf(conv3(mL,tid,w3));
  }
  __syncthreads();
  if(tid<DD){ y4[tid]=s2s[tid]*ws[W_RM4+tid]; y5[tid]=s3s[tid]*ws[W_RM5+tid]; }
  __syncthreads();
  if(tid<DD){
    s4s[tid]=sigf(conv3(y4,tid,w4));
    s5s[tid]=sigf(conv3(y5,tid,w5));
    ws[W_S1+tid]=s1s[tid];
  }
  __syncthreads();
  for(int e=tid;e<DD*NC;e+=256){
    int d=e/NC;
    ws[W_H+e]=s4s[d]*s2s[d]*ws[W_RAWMH+e];
    ws[W_L+e]=s5s[d]*s3s[d]*ws[W_RAWML+e];
  }
  __syncthreads();
  if(tid<DD){
    float s=0.f;
    for(int j=0;j<NC;j++) s+=ws[W_H+tid*NC+j];
    ws[W_HBAR+tid]=s/(float)NC;
  }
}

// a0 = s1*z0 ; Ldif = mean_j |a0-h_j| ; Lmul = a0*hbar
__global__ void k_a0(const float* z0, float* ws){
  __shared__ float hs[NC];
  int b=blockIdx.x; int d=b>>4; int i=((b&15)<<8)+threadIdx.x;
  if(threadIdx.x<NC) hs[threadIdx.x]=ws[W_H+d*NC+threadIdx.x];
  __syncthreads();
  if(i<LL0){
    float a=ws[W_S1+d]*z0[i*DD+d];
    float s=0.f;
    #pragma unroll
    for(int j=0;j<NC;j++) s+=fabsf(a-hs[j]);
    ws[W_A0 +d*LL0+i]=a;
    ws[W_LDIF+d*LL0+i]=s*(1.0f/(float)NC);
    ws[W_LMUL+d*LL0+i]=a*ws[W_HBAR+d];
  }
}

// stage per-position vectors (i0, i0+1) into LDS aw[276]
__device__ __forceinline__ void stage_aw(float* aw, const float* __restrict__ ws,
                                         int i0, int tid){
  if(tid<92){
    int ii=tid/46, dd=tid-46*(tid/46);
    int i=i0+ii; if(i>LL0-1) i=LL0-1;
    aw[tid]     = ws[W_A0  + dd*LL0 + i];
    aw[92+tid]  = ws[W_LDIF+ dd*LL0 + i];
    aw[184+tid] = ws[W_LMUL+ dd*LL0 + i];
  }
}

// build X[NT][96] bf16 tile; h/l read direct from global (L1-resident after 1st tile)
__device__ __forceinline__ void build_X(unsigned short* Xl, const float* aw,
                                        const float* __restrict__ ws,
                                        int n0, int i0, int tid){
  int ib1=(i0+1)*100;
  for(int e=tid;e<NT*46;e+=256){
    int n=e/46, dd=e-n*46;
    int ncol=n0+n;
    int ii=(ncol>=ib1)?1:0;
    int j=ncol-i0*100-ii*100;
    float x1,x2;
    if(j<NC){
      float a=aw[ii*46+dd];
      float hv=ws[W_H+dd*NC+j];
      x1=fabsf(a-hv); x2=a*hv;
    }else{
      float lv=ws[W_L+dd*NC+(j-NC)];
      x1=fabsf(aw[92+ii*46+dd]-lv);
      x2=fabsf(aw[184+ii*46+dd]-lv);
    }
    Xl[n*XROW+dd]   =f2bf(x1);
    Xl[n*XROW+46+dd]=f2bf(x2);
  }
}

// pass A (persistent): gemm1 + relu + BN1 stats
__global__ __launch_bounds__(256,3) void k_gemmA(const float* __restrict__ ws,
                                                 const float* __restrict__ conv_b,
                                                 float* __restrict__ bnsum){
  __shared__ unsigned short Xl[NT*XROW];
  __shared__ float aw[276];
  __shared__ float bnred[512];
  int tid=threadIdx.x;
  int l=tid&63, w=tid>>6, lr=l&15, hi=l>>4, mb=w*64;
  const unsigned short* W1bf=(const unsigned short*)(ws+W_W1BF);
  // zero K-pad cols 92..95 once (never overwritten)
  for(int e=tid;e<NT*4;e+=256){ int n=e>>2; Xl[n*XROW+92+(e&3)]=0; }
  float bb[4][4];
  #pragma unroll
  for(int tm=0;tm<4;tm++)
    #pragma unroll
    for(int r=0;r<4;r++) bb[tm][r]=conv_b[mb+tm*16+hi*4+r];
  float s[4][4], q[4][4];
  #pragma unroll
  for(int tm=0;tm<4;tm++)
    #pragma unroll
    for(int r=0;r<4;r++){ s[tm][r]=0.f; q[tm][r]=0.f; }

  for(int t=blockIdx.x;t<TILES;t+=GRIDP){
    int n0=t*NT, i0=n0/100;
    stage_aw(aw,ws,i0,tid);
    __syncthreads();
    build_X(Xl,aw,ws,n0,i0,tid);
    __syncthreads();
    f32x4 acc[4][4];
    #pragma unroll
    for(int tm=0;tm<4;tm++)
      #pragma unroll
      for(int tn=0;tn<4;tn++) acc[tm][tn]=(f32x4){0.f,0.f,0.f,0.f};
    #pragma unroll
    for(int ks=0;ks<3;ks++){
      bf8 a[4],b[4];
      #pragma unroll
      for(int tm=0;tm<4;tm++)
        a[tm]=*(const bf8*)(W1bf + (mb+tm*16+lr)*96 + ks*32 + hi*8);
      #pragma unroll
      for(int tn=0;tn<4;tn++)
        b[tn]=*(const bf8*)(Xl + (tn*16+lr)*XROW + ks*32 + hi*8);
      #pragma unroll
      for(int tm=0;tm<4;tm++)
        #pragma unroll
        for(int tn=0;tn<4;tn++)
          acc[tm][tn]=__builtin_amdgcn_mfma_f32_16x16x32_bf16(a[tm],b[tn],acc[tm][tn],0,0,0);
    }
    #pragma unroll
    for(int tm=0;tm<4;tm++)
      #pragma unroll
      for(int tn=0;tn<4;tn++)
        #pragma unroll
        for(int r=0;r<4;r++){
          float v=fmaxf(acc[tm][tn][r]+bb[tm][r],0.f);
          s[tm][r]+=v; q[tm][r]+=v*v;
        }
    __syncthreads();
  }
  #pragma unroll
  for(int m=1;m<16;m<<=1)
    #pragma unroll
    for(int tm=0;tm<4;tm++)
      #pragma unroll
      for(int r=0;r<4;r++){
        s[tm][r]+=__shfl_xor(s[tm][r],m);
        q[tm][r]+=__shfl_xor(q[tm][r],m);
      }
  if(lr==0){
    #pragma unroll
    for(int tm=0;tm<4;tm++)
      #pragma unroll
      for(int r=0;r<4;r++){
        int o=mb+tm*16+hi*4+r;
        bnred[o]=s[tm][r]; bnred[256+o]=q[tm][r];
      }
  }
  __syncthreads();
  for(int t=tid;t<512;t+=256) atomicAdd(&bnsum[t],bnred[t]);
}

// BN params: scale = g*rsqrt(var+eps), shift = b - mu*scale
__global__ void k_bnparams(float* ws, const float* g, const float* b,
                           int nch, int sumoff, int scoff){
  int o=threadIdx.x;
  if(o<nch){
    float mu =ws[sumoff+o]    *(1.0f/(float)NPOS);
    float ex2=ws[sumoff+nch+o]*(1.0f/(float)NPOS);
    float var=ex2-mu*mu; if(var<0.f) var=0.f;
    float sc=g[o]*rsqrtf(var+EPSV);
    ws[scoff+o]=sc;
    ws[scoff+nch+o]=b[o]-mu*sc;
  }
}

// pass B (persistent): gemm1 -> relu -> bf16 LDS -> gemm2 (BN1 folded) -> relu
//                      -> out store + BN2 stats
__global__ __launch_bounds__(256,3) void k_gemmB(const float* __restrict__ ws,
      const float* __restrict__ conv_b, float* __restrict__ out,
      float* __restrict__ bn2sum){
  __shared__ unsigned short Xl[NT*XROW];     // 13312 B
  __shared__ unsigned short C1s[NT*C1ROW];   // 33792 B
  __shared__ float aw[276];                  // 1104 B
  __shared__ float bnred[256];               // 1024 B
  int tid=threadIdx.x;
  int l=tid&63, w=tid>>6, lr=l&15, hi=l>>4, mb=w*64, mb2=w*32;
  const unsigned short* W1bf=(const unsigned short*)(ws+W_W1BF);
  const unsigned short* W2bf=(const unsigned short*)(ws+W_W2BF);
  const float* bias2=ws+W_BIAS2;
  for(int e=tid;e<NT*4;e+=256){ int n=e>>2; Xl[n*XROW+92+(e&3)]=0; }
  float bb[4][4];
  #pragma unroll
  for(int tm=0;tm<4;tm++)
    #pragma unroll
    for(int r=0;r<4;r++) bb[tm][r]=conv_b[mb+tm*16+hi*4+r];
  float bb2[2][4];
  #pragma unroll
  for(int tm=0;tm<2;tm++)
    #pragma unroll
    for(int r=0;r<4;r++) bb2[tm][r]=bias2[mb2+tm*16+hi*4+r];
  float s2[2][4], q2[2][4];
  #pragma unroll
  for(int tm=0;tm<2;tm++)
    #pragma unroll
    for(int r=0;r<4;r++){ s2[tm][r]=0.f; q2[tm][r]=0.f; }

  for(int t=blockIdx.x;t<TILES;t+=GRIDP){
    int n0=t*NT, i0=n0/100;
    stage_aw(aw,ws,i0,tid);
    __syncthreads();
    build_X(Xl,aw,ws,n0,i0,tid);
    __syncthreads();
    // gemm1
    f32x4 acc[4][4];
    #pragma unroll
    for(int tm=0;tm<4;tm++)
      #pragma unroll
      for(int tn=0;tn<4;tn++) acc[tm][tn]=(f32x4){0.f,0.f,0.f,0.f};
    #pragma unroll
    for(int ks=0;ks<3;ks++){
      bf8 a[4],b[4];
      #pragma unroll
      for(int tm=0;tm<4;tm++)
        a[tm]=*(const bf8*)(W1bf + (mb+tm*16+lr)*96 + ks*32 + hi*8);
      #pragma unroll
      for(int tn=0;tn<4;tn++)
        b[tn]=*(const bf8*)(Xl + (tn*16+lr)*XROW + ks*32 + hi*8);
      #pragma unroll
      for(int tm=0;tm<4;tm++)
        #pragma unroll
        for(int tn=0;tn<4;tn++)
          acc[tm][tn]=__builtin_amdgcn_mfma_f32_16x16x32_bf16(a[tm],b[tn],acc[tm][tn],0,0,0);
    }
    // relu + bias + pack to C1s[n][o]
    #pragma unroll
    for(int tm=0;tm<4;tm++)
      #pragma unroll
      for(int tn=0;tn<4;tn++){
        int n=tn*16+lr, ob=mb+tm*16+hi*4;
        float v0=fmaxf(acc[tm][tn][0]+bb[tm][0],0.f);
        float v1=fmaxf(acc[tm][tn][1]+bb[tm][1],0.f);
        float v2=fmaxf(acc[tm][tn][2]+bb[tm][2],0.f);
        float v3=fmaxf(acc[tm][tn][3]+bb[tm][3],0.f);
        uint2 pv; pv.x=pk2bf(v0,v1); pv.y=pk2bf(v2,v3);
        *(uint2*)&C1s[n*C1ROW+ob]=pv;
      }
    __syncthreads();
    // gemm2
    f32x4 acc2[2][4];
    #pragma unroll
    for(int tm=0;tm<2;tm++)
      #pragma unroll
      for(int tn=0;tn<4;tn++) acc2[tm][tn]=(f32x4){0.f,0.f,0.f,0.f};
    #pragma unroll
    for(int ks=0;ks<8;ks++){
      bf8 a[2],b[4];
      #pragma unroll
      for(int tm=0;tm<2;tm++)
        a[tm]=*(const bf8*)(W2bf + (mb2+tm*16+lr)*HC + ks*32 + hi*8);
      #pragma unroll
      for(int tn=0;tn<4;tn++)
        b[tn]=*(const bf8*)(C1s + (tn*16+lr)*C1ROW + ks*32 + hi*8);
      #pragma unroll
      for(int tm=0;tm<2;tm++)
        #pragma unroll
        for(int tn=0;tn<4;tn++)
          acc2[tm][tn]=__builtin_amdgcn_mfma_f32_16x16x32_bf16(a[tm],b[tn],acc2[tm][tn],0,0,0);
    }
    // epilogue: relu + store + stats
    #pragma unroll
    for(int tm=0;tm<2;tm++)
      #pragma unroll
      for(int tn=0;tn<4;tn++)
        #pragma unroll
        for(int r=0;r<4;r++){
          float v=fmaxf(acc2[tm][tn][r]+bb2[tm][r],0.f);
          out[(size_t)(mb2+tm*16+hi*4+r)*(size_t)NPOS + (size_t)(n0+tn*16+lr)]=v;
          s2[tm][r]+=v; q2[tm][r]+=v*v;
        }
  }
  #pragma unroll
  for(int m=1;m<16;m<<=1)
    #pragma unroll
    for(int tm=0;tm<2;tm++)
      #pragma unroll
      for(int r=0;r<4;r++){
        s2[tm][r]+=__shfl_xor(s2[tm][r],m);
        q2[tm][r]+=__shfl_xor(q2[tm][r],m);
      }
  if(lr==0){
    #pragma unroll
    for(int tm=0;tm<2;tm++)
      #pragma unroll
      for(int r=0;r<4;r++){
        int o=mb2+tm*16+hi*4+r;
        bnred[o]=s2[tm][r]; bnred[128+o]=q2[tm][r];
      }
  }
  __syncthreads();
  if(tid<256) atomicAdd(&bn2sum[tid],bnred[tid]);
}

// pass C: in-place BN2 affine on d_out
__global__ void k_passC(float* out, const float* ws){
  int idx=blockIdx.x*256+threadIdx.x;
  int stride=gridDim.x*256;
  const int n4=H2C*NPOS/4;
  float4* o4=(float4*)out;
  for(int e=idx;e<n4;e+=stride){
    int o2=e/(NPOS/4);
    float sc=ws[W_SC2+o2], sh=ws[W_SC2+H2C+o2];
    float4 v=o4[e];
    v.x=v.x*sc+sh; v.y=v.y*sc+sh; v.z=v.z*sc+sh; v.w=v.w*sc+sh;
    o4[e]=v;
  }
}

extern "C" void kernel_launch(void* const* d_in, const int* in_sizes, int n_in,
                              void* d_out, int out_size, void* d_ws, size_t ws_size,
                              hipStream_t stream){
  const float* z0     =(const float*)d_in[0];
  const float* z1     =(const float*)d_in[1];
  const float* we1    =(const float*)d_in[2];
  const float* we2    =(const float*)d_in[3];
  const float* we3    =(const float*)d_in[4];
  const float* we4    =(const float*)d_in[5];
  const float* we5    =(const float*)d_in[6];
  const float* conv_w =(const float*)d_in[7];
  const float* conv_b =(const float*)d_in[8];
  const float* bn_g   =(const float*)d_in[9];
  const float* bn_b   =(const float*)d_in[10];
  const float* conv2_w=(const float*)d_in[11];
  const float* conv2_b=(const float*)d_in[12];
  const float* bn2_g  =(const float*)d_in[13];
  const float* bn2_b  =(const float*)d_in[14];
  const int* cdrH=(const int*)d_in[15];
  const int* cdrL=(const int*)d_in[16];
  const int* notH=(const int*)d_in[17];
  const int* notL=(const int*)d_in[18];
  int nCdrH=in_sizes[15], nCdrL=in_sizes[16], nNotH=in_sizes[17], nNotL=in_sizes[18];
  float* ws=(float*)d_ws;
  float* out=(float*)d_out;

  hipLaunchKernelGGL(k_zero,     dim3(1),     dim3(256),0,stream, ws);
  hipLaunchKernelGGL(k_prep,     dim3(96),    dim3(256),0,stream, conv_w,ws);
  hipLaunchKernelGGL(k_colmeans, dim3(DD),    dim3(256),0,stream, z0,z1,ws);
  hipLaunchKernelGGL(k_pairmeans,dim3(DD),    dim3(256),0,stream, z1,cdrH,notH,cdrL,notL,
                     nCdrH,nNotH,nCdrL,nNotL,ws);
  hipLaunchKernelGGL(k_scales,   dim3(1),     dim3(256),0,stream, we1,we2,we3,we4,we5,ws);
  hipLaunchKernelGGL(k_a0,       dim3(DD*16), dim3(256),0,stream, z0,ws);
  hipLaunchKernelGGL(k_gemmA,    dim3(GRIDP), dim3(256),0,stream, ws,conv_b, ws+W_BN1S);
  hipLaunchKernelGGL(k_bnparams, dim3(1),     dim3(256),0,stream, ws,bn_g,bn_b, HC, W_BN1S, W_SC1);
  hipLaunchKernelGGL(k_prep2,    dim3(H2C),   dim3(256),0,stream, conv2_w,conv2_b,ws);
  hipLaunchKernelGGL(k_gemmB,    dim3(GRIDP), dim3(256),0,stream, ws,conv_b, out, ws+W_BN2S);
  hipLaunchKernelGGL(k_bnparams, dim3(1),     dim3(256),0,stream, ws,bn2_g,bn2_b, H2C, W_BN2S, W_SC2);
  hipLaunchKernelGGL(k_passC,    dim3(2048),  dim3(256),0,stream, out, ws);
}

// Round 5
// 327.832 us; speedup vs baseline: 9.1498x; 1.1545x over previous
//
#include <hip/hip_runtime.h>
#include <math.h>

#define DD   46
#define LL0  4000
#define LL1  600
#define CATV 250
#define NC   50
#define NJ   100
#define HC   256
#define H2C  128
#define NPOS (LL0*NJ)
#define EPSV 1e-5f
#define NT   64
#define XROW 104
#define C1ROW 264
#define TILES (NPOS/NT)   // 6250
#define GRIDP 768

// ---- workspace float offsets ----
#define W_MEAN0   0
#define W_MEANH   64
#define W_MEANL   128
#define W_RM4     192
#define W_RM5     256
#define W_S1      320
#define W_HBAR    384
#define W_RAWMH   448
#define W_RAWML   (W_RAWMH+2304)      // 2752
#define W_H       (W_RAWML+2304)      // 5056  [d][50] f32
#define W_L       (W_H+2304)          // 7360
#define W_BN1S    (W_L+2304)          // 9664: 256 sum + 256 sumsq
#define W_SC1     (W_BN1S+512)        // 10176: 256 scale + 256 shift
#define W_BN2S    (W_SC1+512)         // 10688: 128+128
#define W_SC2     (W_BN2S+256)        // 10944: 128+128 -> end 11200
#define W_AWT     11264               // [4001][144]: a0|dif|mul each 48-padded
#define W_W1P     (W_AWT+4001*144)    // 587408: 256*96 bf16 = 12288 floats
#define W_W2BF    (W_W1P+12288)       // 599696: 128*256 bf16 = 16384 floats
#define W_BIAS2   (W_W2BF+16384)      // 616080: 128 floats
#define W_C2P     616448              // 64*NPOS u32 (c2 bf16 pairs) = 102.4 MB

typedef __attribute__((ext_vector_type(8))) short bf8;
typedef __attribute__((ext_vector_type(4))) float f32x4;

__device__ __forceinline__ float sigf(float x){ return 1.0f/(1.0f+__expf(-x)); }

__device__ __forceinline__ unsigned short f2bf(float f){
  unsigned u = __float_as_uint(f);
  return (unsigned short)((u + 0x7FFFu + ((u>>16)&1u)) >> 16);
}
__device__ __forceinline__ unsigned pk2bf(float a, float b){
  return ((unsigned)f2bf(b)<<16) | (unsigned)f2bf(a);
}
__device__ __forceinline__ float bf2f(unsigned short h){
  return __uint_as_float(((unsigned)h)<<16);
}

__device__ float blockReduceSum(float v, float* sm){
  int tid=threadIdx.x;
  sm[tid]=v; __syncthreads();
  for(int s=128;s>0;s>>=1){ if(tid<s) sm[tid]+=sm[tid+s]; __syncthreads(); }
  float r=sm[0]; __syncthreads();
  return r;
}

__global__ void k_zero(float* ws){
  for(int e=threadIdx.x;e<1536;e+=256) ws[W_BN1S+e]=0.f;
}

// W1 -> bf16 permuted: W1p[o][2d+p] = conv_w[o][p?46+d:d], pad c>=92 -> 0
__global__ void k_prep(const float* __restrict__ conv_w, float* __restrict__ ws){
  int t=blockIdx.x*256+threadIdx.x;
  if(t<HC*96){
    int o=t/96, c=t-o*96;
    unsigned short v=0;
    if(c<92){ int d=c>>1, p=c&1; v=f2bf(conv_w[o*92 + (p? 46+d : d)]); }
    ((unsigned short*)(ws+W_W1P))[t]=v;
  }
}

// W2' = W2*sc1 (bf16), bias2' = b2 + sum_k W2[o2,k]*sh1[k]
__global__ void k_prep2(const float* __restrict__ conv2_w, const float* __restrict__ conv2_b,
                        float* __restrict__ ws){
  __shared__ float sm[256];
  int o2=blockIdx.x, t=threadIdx.x;
  float wv=conv2_w[o2*HC+t];
  float sc=ws[W_SC1+t], sh=ws[W_SC1+HC+t];
  ((unsigned short*)(ws+W_W2BF))[o2*HC+t]=f2bf(wv*sc);
  float r=blockReduceSum(wv*sh,sm);
  if(t==0) ws[W_BIAS2+o2]=conv2_b[o2]+r;
}

__global__ void k_colmeans(const float* z0, const float* z1, float* ws){
  __shared__ float sm[256];
  int d=blockIdx.x, tid=threadIdx.x;
  float s0=0.f; for(int i=tid;i<LL0;i+=256) s0+=z0[i*DD+d];
  float sH=0.f; for(int k=tid;k<CATV;k+=256) sH+=z1[k*DD+d];
  float sL=0.f; for(int k=CATV+tid;k<LL1;k+=256) sL+=z1[k*DD+d];
  float r0=blockReduceSum(s0,sm);
  float rH=blockReduceSum(sH,sm);
  float rL=blockReduceSum(sL,sm);
  if(tid==0){
    ws[W_MEAN0+d]=r0/(float)LL0;
    ws[W_MEANH+d]=rH/(float)CATV;
    ws[W_MEANL+d]=rL/(float)(LL1-CATV);
  }
}

__global__ void k_pairmeans(const float* z1, const int* cdrH, const int* notH,
                            const int* cdrL, const int* notL,
                            int nCdrH,int nNotH,int nCdrL,int nNotL, float* ws){
  __shared__ float v[LL1];
  __shared__ float sm[256];
  int d=blockIdx.x, tid=threadIdx.x;
  for(int k=tid;k<LL1;k+=256) v[k]=z1[k*DD+d];
  __syncthreads();
  float partH=0.f, partL=0.f;
  for(int i=tid;i<nCdrH;i+=256){
    float c=v[cdrH[i]]; float s=0.f;
    for(int j=0;j<nNotH;j++) s+=fabsf(c-v[notH[j]]);
    s/= (float)nNotH;
    ws[W_RAWMH+d*NC+i]=s; partH+=s;
  }
  for(int i=tid;i<nCdrL;i+=256){
    float c=v[CATV+cdrL[i]]; float s=0.f;
    for(int j=0;j<nNotL;j++) s+=fabsf(c-v[CATV+notL[j]]);
    s/= (float)nNotL;
    ws[W_RAWML+d*NC+i]=s; partL+=s;
  }
  float rH=blockReduceSum(partH,sm);
  float rL=blockReduceSum(partL,sm);
  if(tid==0){ ws[W_RM4+d]=rH/(float)nCdrH; ws[W_RM5+d]=rL/(float)nCdrL; }
}

__device__ __forceinline__ float conv3(const float* a, int d, const float* w){
  float acc = w[1]*a[d];
  if(d>0)    acc += w[0]*a[d-1];
  if(d<DD-1) acc += w[2]*a[d+1];
  return acc;
}

__global__ void k_scales(const float* w1,const float* w2,const float* w3,
                         const float* w4,const float* w5, float* ws){
  __shared__ float m0[DD], mH[DD], mL[DD];
  __shared__ float s1s[DD],s2s[DD],s3s[DD],s4s[DD],s5s[DD],y4[DD],y5[DD];
  int tid=threadIdx.x;
  if(tid<DD){ m0[tid]=ws[W_MEAN0+tid]; mH[tid]=ws[W_MEANH+tid]; mL[tid]=ws[W_MEANL+tid]; }
  __syncthreads();
  if(tid<DD){
    s1s[tid]=sigf(conv3(m0,tid,w1));
    s2s[tid]=sigf(conv3(mH,tid,w2));
    s3s[tid]=sigf(conv3(mL,tid,w3));
  }
  __syncthreads();
  if(tid<DD){ y4[tid]=s2s[tid]*ws[W_RM4+tid]; y5[tid]=s3s[tid]*ws[W_RM5+tid]; }
  __syncthreads();
  if(tid<DD){
    s4s[tid]=sigf(conv3(y4,tid,w4));
    s5s[tid]=sigf(conv3(y5,tid,w5));
    ws[W_S1+tid]=s1s[tid];
  }
  __syncthreads();
  for(int e=tid;e<DD*NC;e+=256){
    int d=e/NC;
    ws[W_H+e]=s4s[d]*s2s[d]*ws[W_RAWMH+e];
    ws[W_L+e]=s5s[d]*s3s[d]*ws[W_RAWML+e];
  }
  __syncthreads();
  if(tid<DD){
    float s=0.f;
    for(int j=0;j<NC;j++) s+=ws[W_H+tid*NC+j];
    ws[W_HBAR+tid]=s/(float)NC;
  }
}

// AWt[i][144] = { a0[48] | dif[48] | mul[48] }, transposed + padded
__global__ void k_aw(const float* __restrict__ z0, float* __restrict__ ws){
  int e=blockIdx.x*256+threadIdx.x;
  if(e>=LL0*48) return;
  int i=e/48, d=e-48*i;
  float a=0.f, df=0.f, ml=0.f;
  if(d<DD){
    a = ws[W_S1+d]*z0[i*DD+d];
    float s=0.f;
    #pragma unroll 10
    for(int j=0;j<NC;j++) s+=fabsf(a-ws[W_H+d*NC+j]);
    df = s*(1.0f/(float)NC);
    ml = a*ws[W_HBAR+d];
  }
  ws[W_AWT + i*144 + d]      = a;
  ws[W_AWT + i*144 + 48 + d] = df;
  ws[W_AWT + i*144 + 96 + d] = ml;
}

// stage bf16 h/l tables [j][48] into LDS (once per block)
__device__ __forceinline__ void stage_tables(unsigned short* hT, unsigned short* lT,
                                             const float* __restrict__ ws, int tid){
  for(int t=tid;t<2400;t+=256){
    int j=t/48, d=t-48*j;
    hT[t] = (d<DD)? f2bf(ws[W_H + d*NC + j]) : (unsigned short)0;
    lT[t] = (d<DD)? f2bf(ws[W_L + d*NC + j]) : (unsigned short)0;
  }
}

// build X tile: Xl[n][2d+p] bf16, vectorized 4-d groups
__device__ __forceinline__ void build_X(unsigned short* Xl, const float* aw,
                                        const unsigned short* hT, const unsigned short* lT,
                                        int n0, int i0, int tid){
  int ibase=i0*100, ib1=ibase+100;
  for(int e=tid;e<NT*12;e+=256){
    int n=e/12, g=e-12*n, d4=g*4;
    int ncol=n0+n;
    int ii=(ncol>=ib1)?1:0;
    int j=ncol-ibase-ii*100;
    const float* ar=aw+ii*144;
    float x10,x11,x12,x13, x20,x21,x22,x23;
    if(j<NC){
      float4 a=*(const float4*)(ar+d4);
      ushort4 hb=*(const ushort4*)(hT+j*48+d4);
      float h0=bf2f(hb.x),h1=bf2f(hb.y),h2=bf2f(hb.z),h3=bf2f(hb.w);
      x10=fabsf(a.x-h0); x20=a.x*h0;
      x11=fabsf(a.y-h1); x21=a.y*h1;
      x12=fabsf(a.z-h2); x22=a.z*h2;
      x13=fabsf(a.w-h3); x23=a.w*h3;
    }else{
      float4 df=*(const float4*)(ar+48+d4);
      float4 ml=*(const float4*)(ar+96+d4);
      ushort4 lb=*(const ushort4*)(lT+(j-NC)*48+d4);
      float l0=bf2f(lb.x),l1=bf2f(lb.y),l2=bf2f(lb.z),l3=bf2f(lb.w);
      x10=fabsf(df.x-l0); x20=fabsf(ml.x-l0);
      x11=fabsf(df.y-l1); x21=fabsf(ml.y-l1);
      x12=fabsf(df.z-l2); x22=fabsf(ml.z-l2);
      x13=fabsf(df.w-l3); x23=fabsf(ml.w-l3);
    }
    uint4 pv;
    pv.x=pk2bf(x10,x20); pv.y=pk2bf(x11,x21); pv.z=pk2bf(x12,x22); pv.w=pk2bf(x13,x23);
    *(uint4*)(Xl + n*XROW + 8*g) = pv;
  }
}

__device__ __forceinline__ void gemm1_tile(const bf8 w1f[4][3], const unsigned short* Xl,
                                           int lr,int hi, f32x4 acc[4][4]){
  #pragma unroll
  for(int tm=0;tm<4;tm++)
    #pragma unroll
    for(int tn=0;tn<4;tn++) acc[tm][tn]=(f32x4){0.f,0.f,0.f,0.f};
  #pragma unroll
  for(int ks=0;ks<3;ks++){
    bf8 b[4];
    #pragma unroll
    for(int tn=0;tn<4;tn++)
      b[tn]=*(const bf8*)(Xl + (tn*16+lr)*XROW + ks*32 + hi*8);
    #pragma unroll
    for(int tm=0;tm<4;tm++)
      #pragma unroll
      for(int tn=0;tn<4;tn++)
        acc[tm][tn]=__builtin_amdgcn_mfma_f32_16x16x32_bf16(w1f[tm][ks],b[tn],acc[tm][tn],0,0,0);
  }
}

// pass A (persistent): build + gemm1 + BN1 stats
__global__ __launch_bounds__(256,3) void k_gemmA(const float* __restrict__ ws,
                                                 const float* __restrict__ conv_b,
                                                 float* __restrict__ bnsum){
  __shared__ unsigned short hT[2400], lT[2400];
  __shared__ float aw[288];
  __shared__ unsigned short Xl[NT*XROW];
  __shared__ float bnred[512];
  int tid=threadIdx.x;
  int l=tid&63, w=tid>>6, lr=l&15, hi=l>>4, mb=w*64;
  stage_tables(hT,lT,ws,tid);
  const unsigned short* W1p=(const unsigned short*)(ws+W_W1P);
  bf8 w1f[4][3];
  #pragma unroll
  for(int tm=0;tm<4;tm++)
    #pragma unroll
    for(int ks=0;ks<3;ks++)
      w1f[tm][ks]=*(const bf8*)(W1p + (mb+tm*16+lr)*96 + ks*32 + hi*8);
  float bb[4][4];
  #pragma unroll
  for(int tm=0;tm<4;tm++)
    #pragma unroll
    for(int r=0;r<4;r++) bb[tm][r]=conv_b[mb+tm*16+hi*4+r];
  float s[4][4], q[4][4];
  #pragma unroll
  for(int tm=0;tm<4;tm++)
    #pragma unroll
    for(int r=0;r<4;r++){ s[tm][r]=0.f; q[tm][r]=0.f; }
  __syncthreads();

  for(int t=blockIdx.x;t<TILES;t+=GRIDP){
    int n0=t*NT, i0=n0/100;
    if(tid<72) ((float4*)aw)[tid]=*(const float4*)(ws + W_AWT + i0*144 + tid*4);
    __syncthreads();
    build_X(Xl,aw,hT,lT,n0,i0,tid);
    __syncthreads();
    f32x4 acc[4][4];
    gemm1_tile(w1f,Xl,lr,hi,acc);
    #pragma unroll
    for(int tm=0;tm<4;tm++)
      #pragma unroll
      for(int tn=0;tn<4;tn++)
        #pragma unroll
        for(int r=0;r<4;r++){
          float v=fmaxf(acc[tm][tn][r]+bb[tm][r],0.f);
          s[tm][r]+=v; q[tm][r]+=v*v;
        }
    __syncthreads();
  }
  #pragma unroll
  for(int m=1;m<16;m<<=1)
    #pragma unroll
    for(int tm=0;tm<4;tm++)
      #pragma unroll
      for(int r=0;r<4;r++){
        s[tm][r]+=__shfl_xor(s[tm][r],m);
        q[tm][r]+=__shfl_xor(q[tm][r],m);
      }
  if(lr==0){
    #pragma unroll
    for(int tm=0;tm<4;tm++)
      #pragma unroll
      for(int r=0;r<4;r++){
        int o=mb+tm*16+hi*4+r;
        bnred[o]=s[tm][r]; bnred[256+o]=q[tm][r];
      }
  }
  __syncthreads();
  for(int t=tid;t<512;t+=256) atomicAdd(&bnsum[t],bnred[t]);
}

__global__ void k_bnparams(float* ws, const float* g, const float* b,
                           int nch, int sumoff, int scoff){
  int o=threadIdx.x;
  if(o<nch){
    float mu =ws[sumoff+o]    *(1.0f/(float)NPOS);
    float ex2=ws[sumoff+nch+o]*(1.0f/(float)NPOS);
    float var=ex2-mu*mu; if(var<0.f) var=0.f;
    float sc=g[o]*rsqrtf(var+EPSV);
    ws[scoff+o]=sc;
    ws[scoff+nch+o]=b[o]-mu*sc;
  }
}

// pass B (persistent): build+gemm1+pack+gemm2+stats2; c2 bf16-pairs to ws (fast)
// or f32 pre-BN2 to out (fallback)
__global__ __launch_bounds__(256,3) void k_gemmB(const float* __restrict__ ws,
      const float* __restrict__ conv_b, float* __restrict__ out,
      unsigned* __restrict__ c2u, int fastc2, float* __restrict__ bn2sum){
  __shared__ unsigned short hT[2400], lT[2400];
  __shared__ float aw[288];
  __shared__ unsigned short BUF[NT*C1ROW];   // union: Xl (NT*XROW) / C1s (NT*C1ROW)
  __shared__ float bnred[256];
  int tid=threadIdx.x;
  int l=tid&63, w=tid>>6, lr=l&15, hi=l>>4, mb=w*64, mb2=w*32;
  stage_tables(hT,lT,ws,tid);
  const unsigned short* W1p=(const unsigned short*)(ws+W_W1P);
  const unsigned short* W2bf=(const unsigned short*)(ws+W_W2BF);
  const float* bias2=ws+W_BIAS2;
  bf8 w1f[4][3];
  #pragma unroll
  for(int tm=0;tm<4;tm++)
    #pragma unroll
    for(int ks=0;ks<3;ks++)
      w1f[tm][ks]=*(const bf8*)(W1p + (mb+tm*16+lr)*96 + ks*32 + hi*8);
  float bb[4][4];
  #pragma unroll
  for(int tm=0;tm<4;tm++)
    #pragma unroll
    for(int r=0;r<4;r++) bb[tm][r]=conv_b[mb+tm*16+hi*4+r];
  float bb2[2][4];
  #pragma unroll
  for(int tm=0;tm<2;tm++)
    #pragma unroll
    for(int r=0;r<4;r++) bb2[tm][r]=bias2[mb2+tm*16+hi*4+r];
  float s2[2][4], q2[2][4];
  #pragma unroll
  for(int tm=0;tm<2;tm++)
    #pragma unroll
    for(int r=0;r<4;r++){ s2[tm][r]=0.f; q2[tm][r]=0.f; }
  __syncthreads();

  for(int t=blockIdx.x;t<TILES;t+=GRIDP){
    int n0=t*NT, i0=n0/100;
    if(tid<72) ((float4*)aw)[tid]=*(const float4*)(ws + W_AWT + i0*144 + tid*4);
    __syncthreads();
    build_X(BUF,aw,hT,lT,n0,i0,tid);   // BUF as Xl
    __syncthreads();
    f32x4 acc[4][4];
    gemm1_tile(w1f,BUF,lr,hi,acc);
    __syncthreads();                   // all Xl reads done before C1s overwrite
    #pragma unroll
    for(int tm=0;tm<4;tm++)
      #pragma unroll
      for(int tn=0;tn<4;tn++){
        int n=tn*16+lr, ob=mb+tm*16+hi*4;
        float v0=fmaxf(acc[tm][tn][0]+bb[tm][0],0.f);
        float v1=fmaxf(acc[tm][tn][1]+bb[tm][1],0.f);
        float v2=fmaxf(acc[tm][tn][2]+bb[tm][2],0.f);
        float v3=fmaxf(acc[tm][tn][3]+bb[tm][3],0.f);
        uint2 pv; pv.x=pk2bf(v0,v1); pv.y=pk2bf(v2,v3);
        *(uint2*)&BUF[n*C1ROW+ob]=pv;  // BUF as C1s
      }
    __syncthreads();
    f32x4 acc2[2][4];
    #pragma unroll
    for(int tm=0;tm<2;tm++)
      #pragma unroll
      for(int tn=0;tn<4;tn++) acc2[tm][tn]=(f32x4){0.f,0.f,0.f,0.f};
    #pragma unroll
    for(int ks=0;ks<8;ks++){
      bf8 a[2],b[4];
      #pragma unroll
      for(int tm=0;tm<2;tm++)
        a[tm]=*(const bf8*)(W2bf + (mb2+tm*16+lr)*HC + ks*32 + hi*8);
      #pragma unroll
      for(int tn=0;tn<4;tn++)
        b[tn]=*(const bf8*)(BUF + (tn*16+lr)*C1ROW + ks*32 + hi*8);
      #pragma unroll
      for(int tm=0;tm<2;tm++)
        #pragma unroll
        for(int tn=0;tn<4;tn++)
          acc2[tm][tn]=__builtin_amdgcn_mfma_f32_16x16x32_bf16(a[tm],b[tn],acc2[tm][tn],0,0,0);
    }
    #pragma unroll
    for(int tm=0;tm<2;tm++)
      #pragma unroll
      for(int tn=0;tn<4;tn++){
        float v0=fmaxf(acc2[tm][tn][0]+bb2[tm][0],0.f);
        float v1=fmaxf(acc2[tm][tn][1]+bb2[tm][1],0.f);
        float v2=fmaxf(acc2[tm][tn][2]+bb2[tm][2],0.f);
        float v3=fmaxf(acc2[tm][tn][3]+bb2[tm][3],0.f);
        s2[tm][0]+=v0; q2[tm][0]+=v0*v0;
        s2[tm][1]+=v1; q2[tm][1]+=v1*v1;
        s2[tm][2]+=v2; q2[tm][2]+=v2*v2;
        s2[tm][3]+=v3; q2[tm][3]+=v3*v3;
        int gn=n0+tn*16+lr;
        int ob2=mb2+tm*16+hi*4;
        if(fastc2){
          int q0=ob2>>1;
          c2u[(size_t)q0*NPOS+gn]    =pk2bf(v0,v1);
          c2u[(size_t)(q0+1)*NPOS+gn]=pk2bf(v2,v3);
        }else{
          out[(size_t)(ob2+0)*NPOS+gn]=v0;
          out[(size_t)(ob2+1)*NPOS+gn]=v1;
          out[(size_t)(ob2+2)*NPOS+gn]=v2;
          out[(size_t)(ob2+3)*NPOS+gn]=v3;
        }
      }
    __syncthreads();
  }
  #pragma unroll
  for(int m=1;m<16;m<<=1)
    #pragma unroll
    for(int tm=0;tm<2;tm++)
      #pragma unroll
      for(int r=0;r<4;r++){
        s2[tm][r]+=__shfl_xor(s2[tm][r],m);
        q2[tm][r]+=__shfl_xor(q2[tm][r],m);
      }
  if(lr==0){
    #pragma unroll
    for(int tm=0;tm<2;tm++)
      #pragma unroll
      for(int r=0;r<4;r++){
        int o=mb2+tm*16+hi*4+r;
        bnred[o]=s2[tm][r]; bnred[128+o]=q2[tm][r];
      }
  }
  __syncthreads();
  if(tid<256) atomicAdd(&bn2sum[tid],bnred[tid]);
}

// fast pass C: stream c2 bf16-pairs -> affine -> f32 out (2 rows per uint4)
__global__ void k_passC_fast(float* __restrict__ out, const unsigned* __restrict__ c2u,
                             const float* __restrict__ ws){
  const int NQ4=NPOS/4;                       // uint4 per q-row
  int idx=blockIdx.x*256+threadIdx.x;
  int stride=gridDim.x*256;
  const uint4* c4=(const uint4*)c2u;
  for(int e=idx;e<64*NQ4;e+=stride){
    int qq=e/NQ4, nb=(e-qq*NQ4)*4;
    uint4 v=c4[e];
    float sc0=ws[W_SC2+2*qq],   sh0=ws[W_SC2+H2C+2*qq];
    float sc1=ws[W_SC2+2*qq+1], sh1=ws[W_SC2+H2C+2*qq+1];
    float4 o0,o1;
    o0.x=bf2f((unsigned short)(v.x&0xffff))*sc0+sh0;
    o1.x=bf2f((unsigned short)(v.x>>16))  *sc1+sh1;
    o0.y=bf2f((unsigned short)(v.y&0xffff))*sc0+sh0;
    o1.y=bf2f((unsigned short)(v.y>>16))  *sc1+sh1;
    o0.z=bf2f((unsigned short)(v.z&0xffff))*sc0+sh0;
    o1.z=bf2f((unsigned short)(v.z>>16))  *sc1+sh1;
    o0.w=bf2f((unsigned short)(v.w&0xffff))*sc0+sh0;
    o1.w=bf2f((unsigned short)(v.w>>16))  *sc1+sh1;
    *(float4*)(out+(size_t)(2*qq)*NPOS+nb)  =o0;
    *(float4*)(out+(size_t)(2*qq+1)*NPOS+nb)=o1;
  }
}

// fallback pass C: in-place BN2 affine on d_out
__global__ void k_passC(float* out, const float* ws){
  int idx=blockIdx.x*256+threadIdx.x;
  int stride=gridDim.x*256;
  const int n4=H2C*NPOS/4;
  float4* o4=(float4*)out;
  for(int e=idx;e<n4;e+=stride){
    int o2=e/(NPOS/4);
    float sc=ws[W_SC2+o2], sh=ws[W_SC2+H2C+o2];
    float4 v=o4[e];
    v.x=v.x*sc+sh; v.y=v.y*sc+sh; v.z=v.z*sc+sh; v.w=v.w*sc+sh;
    o4[e]=v;
  }
}

extern "C" void kernel_launch(void* const* d_in, const int* in_sizes, int n_in,
                              void* d_out, int out_size, void* d_ws, size_t ws_size,
                              hipStream_t stream){
  const float* z0     =(const float*)d_in[0];
  const float* z1     =(const float*)d_in[1];
  const float* we1    =(const float*)d_in[2];
  const float* we2    =(const float*)d_in[3];
  const float* we3    =(const float*)d_in[4];
  const float* we4    =(const float*)d_in[5];
  const float* we5    =(const float*)d_in[6];
  const float* conv_w =(const float*)d_in[7];
  const float* conv_b =(const float*)d_in[8];
  const float* bn_g   =(const float*)d_in[9];
  const float* bn_b   =(const float*)d_in[10];
  const float* conv2_w=(const float*)d_in[11];
  const float* conv2_b=(const float*)d_in[12];
  const float* bn2_g  =(const float*)d_in[13];
  const float* bn2_b  =(const float*)d_in[14];
  const int* cdrH=(const int*)d_in[15];
  const int* cdrL=(const int*)d_in[16];
  const int* notH=(const int*)d_in[17];
  const int* notL=(const int*)d_in[18];
  int nCdrH=in_sizes[15], nCdrL=in_sizes[16], nNotH=in_sizes[17], nNotL=in_sizes[18];
  float* ws=(float*)d_ws;
  float* out=(float*)d_out;

  size_t need=((size_t)W_C2P + (size_t)64*NPOS)*4ull;
  int fastc2 = (ws_size>=need) ? 1 : 0;
  unsigned* c2u=(unsigned*)(ws+W_C2P);

  hipLaunchKernelGGL(k_zero,     dim3(1),    dim3(256),0,stream, ws);
  hipLaunchKernelGGL(k_prep,     dim3(96),   dim3(256),0,stream, conv_w,ws);
  hipLaunchKernelGGL(k_colmeans, dim3(DD),   dim3(256),0,stream, z0,z1,ws);
  hipLaunchKernelGGL(k_pairmeans,dim3(DD),   dim3(256),0,stream, z1,cdrH,notH,cdrL,notL,
                     nCdrH,nNotH,nCdrL,nNotL,ws);
  hipLaunchKernelGGL(k_scales,   dim3(1),    dim3(256),0,stream, we1,we2,we3,we4,we5,ws);
  hipLaunchKernelGGL(k_aw,       dim3((LL0*48+255)/256), dim3(256),0,stream, z0,ws);
  hipLaunchKernelGGL(k_gemmA,    dim3(GRIDP),dim3(256),0,stream, ws,conv_b, ws+W_BN1S);
  hipLaunchKernelGGL(k_bnparams, dim3(1),    dim3(256),0,stream, ws,bn_g,bn_b, HC, W_BN1S, W_SC1);
  hipLaunchKernelGGL(k_prep2,    dim3(H2C),  dim3(256),0,stream, conv2_w,conv2_b,ws);
  hipLaunchKernelGGL(k_gemmB,    dim3(GRIDP),dim3(256),0,stream, ws,conv_b, out, c2u, fastc2,
                     ws+W_BN2S);
  hipLaunchKernelGGL(k_bnparams, dim3(1),    dim3(256),0,stream, ws,bn2_g,bn2_b, H2C, W_BN2S, W_SC2);
  if(fastc2){
    hipLaunchKernelGGL(k_passC_fast, dim3(2048), dim3(256),0,stream, out, c2u, ws);
  }else{
    hipLaunchKernelGGL(k_passC,      dim3(2048), dim3(256),0,stream, out, ws);
  }
}